// Round 7
// baseline (595.073 us; speedup 1.0000x reference)
//
#include <hip/hip_runtime.h>
#include <hip/hip_bf16.h>
#include <cstring>

#define N_NODES 50000
#define N_EDGES 800000
#define IN_CH 128
#define NG 500
#define OUT_ELEMS 9782000

using bf16 = __hip_bfloat16;
typedef unsigned short u16;
typedef long long i64;

__device__ __forceinline__ float b2f(bf16 v) { return __bfloat162float(v); }
__device__ __forceinline__ float tofl(float v) { return v; }
__device__ __forceinline__ float tofl(bf16 v) { return __bfloat162float(v); }
__device__ __forceinline__ float ldflt(const void* p, int i, int f32) {
  return f32 ? ((const float*)p)[i] : b2f(((const bf16*)p)[i]);
}
__device__ __forceinline__ int ldedge(const void* p, int i, int is64) {
  return is64 ? (int)((const i64*)p)[i] : ((const int*)p)[i];
}
__device__ __forceinline__ float sane(float v) {
  if (!isfinite(v)) return 0.f;
  return fminf(fmaxf(v, -65504.f), 65504.f);
}
__device__ __forceinline__ float lrelu(float x) { return x > 0.f ? x : 0.2f * x; }

__device__ __forceinline__ float wsum(float v) {
#pragma unroll
  for (int o = 32; o > 0; o >>= 1) v += __shfl_xor(v, o, 64);
  return v;
}
__device__ __forceinline__ float wmax(float v) {
#pragma unroll
  for (int o = 32; o > 0; o >>= 1) v = fmaxf(v, __shfl_xor(v, o, 64));
  return v;
}

// d_out is FLOAT32 (reference output dtype), 9,782,000 f32 = 39,128,000 B.
//   xhat f32 @ elem 0          (6,400,000)  -> bytes [0, 25.6M)
//   ehat f32 @ 6,400,000       (150,000)
//   zreg f32 @ 6,550,000       (3,200,000)  o1 -> o2 -> z in place
//   emb  f32 @ 9,750,000       (32,000)
// Scratch (base = d_ws if ws_size>=11MB else d_out; fits in xhat region):
//   deg/gsum@0 (200,000 B) | cur/gcnt@200,000 | offs@400,000 (200,016)
//   part@600,016 (256) | flags@600,272 (64) | ss@600,448 (200,000)
//   sd@800,448 (200,000) | csr@1,000,448 (3,200,000) | hbuf(bf16)@4,200,448
//   (6,400,000) -> ends 10,600,448 < 25,600,000. xdec overwrites xhat LAST.

__global__ void zero_kernel(int* __restrict__ p, int n) {
  int i = blockIdx.x * 256 + threadIdx.x;
  if (i < n) p[i] = 0;
}

__global__ void fillsig_kernel(float* __restrict__ out, int n, float v) {
  int i = blockIdx.x * 256 + threadIdx.x;
  if (i < n) out[i] = v;
}

// ---- dtype sniffers ----
__global__ void sniff_x_kernel(const u16* __restrict__ xb, int* __restrict__ fl) {
  int i = blockIdx.x * 256 + threadIdx.x;
  if (i < 8192) {
    u16 u = xb[2 * i];
    int e = (u >> 7) & 0xFF;
    if (e != 0 && (e < 90 || e > 150)) atomicAdd(&fl[7], 1);
  }
}
__global__ void sniff_ei_kernel(const int* __restrict__ ei, int* __restrict__ fl) {
  int i = blockIdx.x * 256 + threadIdx.x;
  if (i < 8192 && ei[2 * i + 1] == 0) atomicAdd(&fl[6], 1);
}
__global__ void sniff_fin_kernel(int* __restrict__ fl) {
  if (blockIdx.x == 0 && threadIdx.x == 0) {
    fl[4] = (fl[6] > 4000) ? 1 : 0;  // edge_index/batch are int64
    fl[5] = (fl[7] > 2000) ? 1 : 0;  // float inputs are f32
  }
}

// ---- CSR build ----
__global__ void hist_kernel(const void* __restrict__ ei, const int* __restrict__ fl,
                            int* __restrict__ deg) {
  int is64 = fl[4];
  int e = blockIdx.x * 256 + threadIdx.x;
  if (e < N_EDGES) {
    unsigned d = (unsigned)ldedge(ei, N_EDGES + e, is64);
    if (d < N_NODES) atomicAdd(&deg[d], 1);
  }
}

__global__ __launch_bounds__(1024) void scan1_kernel(const int* __restrict__ deg,
                                                     int* __restrict__ offs,
                                                     int* __restrict__ part, int n) {
  __shared__ int sm[1024];
  int t = threadIdx.x;
  int idx = blockIdx.x * 1024 + t;
  int v = (idx < n) ? deg[idx] : 0;
  sm[t] = v;
  __syncthreads();
  for (int off = 1; off < 1024; off <<= 1) {
    int add = (t >= off) ? sm[t - off] : 0;
    __syncthreads();
    sm[t] += add;
    __syncthreads();
  }
  if (idx < n) offs[idx] = sm[t] - v;
  if (t == 1023) part[blockIdx.x] = sm[1023];
}

__global__ void scan2_kernel(int* __restrict__ part, int* __restrict__ offs, int nb, int n) {
  if (blockIdx.x == 0 && threadIdx.x == 0) {
    int run = 0;
    for (int b = 0; b < nb; ++b) { int t = part[b]; part[b] = run; run += t; }
    offs[n] = run;
  }
}

__global__ void scan3_kernel(int* __restrict__ offs, const int* __restrict__ part, int n) {
  int i = blockIdx.x * 256 + threadIdx.x;
  if (i < n) offs[i] += part[i >> 10];
}

__global__ void scatter_kernel(const void* __restrict__ ei, const int* __restrict__ fl,
                               const int* __restrict__ offs, int* __restrict__ cur,
                               int* __restrict__ csr) {
  int is64 = fl[4];
  int e = blockIdx.x * 256 + threadIdx.x;
  if (e < N_EDGES) {
    unsigned d = (unsigned)ldedge(ei, N_EDGES + e, is64);
    unsigned s = (unsigned)ldedge(ei, e, is64);
    if (d < N_NODES && s < N_NODES) {
      int pos = offs[d] + atomicAdd(&cur[d], 1);
      pos = max(0, min(pos, N_EDGES - 1));
      csr[pos] = (int)s;
    }
  }
}

__global__ void diag_graph_kernel(const int* __restrict__ offs, const int* __restrict__ csr,
                                  int* __restrict__ fl) {
  int i = blockIdx.x * 256 + threadIdx.x;
  if (i < N_NODES && (offs[i] > offs[i + 1] || offs[i] < 0)) atomicOr(&fl[0], 2);
  if (i == 0 && offs[N_NODES] != N_EDGES) atomicOr(&fl[0], 2);
  if (i < N_EDGES && (unsigned)csr[i] >= N_NODES) atomicOr(&fl[0], 4);
}

// ---- GEMM + attention scores: 16 rows/block, 4 rows/wave, lane = out col ----
// Scores ss/sd computed from f32 accumulators (exact); h stored bf16 (scratch).
template <int FIN, typename FT>
__device__ void gemm16_compute(float (&xl)[16][FIN], const void* Wv, const void* asv,
                               const void* adv, bf16* __restrict__ h, float* __restrict__ ss,
                               float* __restrict__ sd, int rbase) {
  const FT* W = (const FT*)Wv;
  const FT* as_ = (const FT*)asv;
  const FT* ad_ = (const FT*)adv;
  int lane = threadIdx.x & 63, w = threadIdx.x >> 6;
  float a_s = tofl(as_[lane]), a_d = tofl(ad_[lane]);
  int r0 = w * 4;
  float acc0 = 0.f, acc1 = 0.f, acc2 = 0.f, acc3 = 0.f;
  for (int k = 0; k < FIN; ++k) {
    float wk = tofl(W[k * 64 + lane]);
    acc0 = fmaf(xl[r0 + 0][k], wk, acc0);
    acc1 = fmaf(xl[r0 + 1][k], wk, acc1);
    acc2 = fmaf(xl[r0 + 2][k], wk, acc2);
    acc3 = fmaf(xl[r0 + 3][k], wk, acc3);
  }
  float acc[4] = {sane(acc0), sane(acc1), sane(acc2), sane(acc3)};
#pragma unroll
  for (int j = 0; j < 4; ++j) {
    int g = rbase + r0 + j;
    h[g * 64 + lane] = __float2bfloat16(acc[j]);
    float vs = wsum(acc[j] * a_s);
    float vd = wsum(acc[j] * a_d);
    if (lane == 0) { ss[g] = sane(vs); sd[g] = sane(vd); }
  }
}

// xmode 0: input x, dtype per fl[5]. xmode 1: internal f32 buffer.
template <int FIN>
__global__ __launch_bounds__(256) void gemm16_kernel(
    const void* __restrict__ xin, int xmode, const void* __restrict__ W,
    const void* __restrict__ asrc, const void* __restrict__ adst, const int* __restrict__ fl,
    bf16* __restrict__ h, float* __restrict__ ss, float* __restrict__ sd) {
  __shared__ float xl[16][FIN];
  int wf = fl[5];
  int xf = xmode ? 1 : wf;
  int tid = threadIdx.x;
  int rbase = blockIdx.x * 16;
  for (int i = tid; i < 16 * FIN; i += 256) {
    int rr = i / FIN, cc = i % FIN;
    xl[rr][cc] = ldflt(xin, (rbase + rr) * FIN + cc, xf);
  }
  __syncthreads();
  if (wf)
    gemm16_compute<FIN, float>(xl, W, asrc, adst, h, ss, sd, rbase);
  else
    gemm16_compute<FIN, bf16>(xl, W, asrc, adst, h, ss, sd, rbase);
}

// ---- GAT softmax-aggregate: one wave per dst node, lane = channel ----
__global__ __launch_bounds__(256) void gat_aggregate_kernel(
    const bf16* __restrict__ h, const float* __restrict__ ss, const float* __restrict__ sd,
    const int* __restrict__ offs, const int* __restrict__ csr, const void* __restrict__ bias,
    const int* __restrict__ fl, float* __restrict__ outp, int do_relu) {
  int wf = fl[5];
  int lane = threadIdx.x & 63, w = threadIdx.x >> 6;
  int d = blockIdx.x * 4 + w;
  float sdd = sd[d];
  float aself = lrelu(ss[d] + sdd);
  int beg = offs[d], end = offs[d + 1];
  beg = max(0, min(beg, N_EDGES));
  end = max(beg, min(end, N_EDGES));
  float m = aself;
  for (int j = beg + lane; j < end; j += 64) {
    int s = csr[j];
    s = ((unsigned)s < N_NODES) ? s : 0;
    m = fmaxf(m, lrelu(ss[s] + sdd));
  }
  m = wmax(m);
  float wself = expf(aself - m);
  float acc = b2f(h[d * 64 + lane]) * wself;
  float dpart = (lane == 0) ? wself : 0.f;
  for (int cb = beg; cb < end; cb += 64) {
    int j = cb + lane;
    int s = 0;
    float wv = 0.f;
    if (j < end) {
      s = csr[j];
      s = ((unsigned)s < N_NODES) ? s : 0;
      wv = expf(lrelu(ss[s] + sdd) - m);
    }
    dpart += wv;
    int cnt = min(64, end - cb);
    for (int t = 0; t < cnt; ++t) {
      float wt = __shfl(wv, t, 64);
      int st = __shfl(s, t, 64);
      acc = fmaf(b2f(h[st * 64 + lane]), wt, acc);
    }
  }
  float denom = wsum(dpart);
  float res = acc / (denom + 1e-16f) + ldflt(bias, lane, wf);
  if (do_relu) res = fmaxf(res, 0.f);
  outp[d * 64 + lane] = sane(res);
}

// ---- z = o2 @ lin_W + lin_b, in place on f32 Z region ----
template <typename FT>
__device__ void lin16_compute(float (&xl)[16][64], const void* Wv, const void* bv,
                              float* __restrict__ zio, int rbase) {
  const FT* W = (const FT*)Wv;
  const FT* b = (const FT*)bv;
  int lane = threadIdx.x & 63, w = threadIdx.x >> 6;
  int r0 = w * 4;
  float bl = tofl(b[lane]);
  float acc0 = bl, acc1 = bl, acc2 = bl, acc3 = bl;
  for (int k = 0; k < 64; ++k) {
    float wk = tofl(W[k * 64 + lane]);
    acc0 = fmaf(xl[r0 + 0][k], wk, acc0);
    acc1 = fmaf(xl[r0 + 1][k], wk, acc1);
    acc2 = fmaf(xl[r0 + 2][k], wk, acc2);
    acc3 = fmaf(xl[r0 + 3][k], wk, acc3);
  }
  float acc[4] = {sane(acc0), sane(acc1), sane(acc2), sane(acc3)};
#pragma unroll
  for (int j = 0; j < 4; ++j) zio[(rbase + r0 + j) * 64 + lane] = acc[j];
}

__global__ __launch_bounds__(256) void linear16_kernel(float* __restrict__ zio,
                                                       const void* __restrict__ W,
                                                       const void* __restrict__ b,
                                                       const int* __restrict__ fl) {
  __shared__ float xl[16][64];
  int wf = fl[5];
  int tid = threadIdx.x;
  int rbase = blockIdx.x * 16;
  for (int i = tid; i < 1024; i += 256) xl[i >> 6][i & 63] = zio[rbase * 64 + i];
  __syncthreads();
  if (wf)
    lin16_compute<float>(xl, W, b, zio, rbase);
  else
    lin16_compute<bf16>(xl, W, b, zio, rbase);
}

// ---- global mean pool ----
__global__ __launch_bounds__(256) void pool_kernel(const float* __restrict__ z,
                                                   const void* __restrict__ batch,
                                                   const int* __restrict__ fl,
                                                   float* __restrict__ gsum,
                                                   float* __restrict__ gcnt) {
  int is64 = fl[4];
  int lane = threadIdx.x & 63, w = threadIdx.x >> 6;
  int n = blockIdx.x * 4 + w;
  unsigned b = (unsigned)ldedge(batch, n, is64);
  if (b >= NG) b = 0;
  atomicAdd(&gsum[b * 64 + lane], z[n * 64 + lane]);
  if (lane == 0) atomicAdd(&gcnt[b], 1.0f);
}

__global__ void embed_kernel(const float* __restrict__ gsum, const float* __restrict__ gcnt,
                             float* __restrict__ out) {
  int i = blockIdx.x * 256 + threadIdx.x;
  if (i < NG * 64) out[i] = sane(gsum[i] / fmaxf(gcnt[i >> 6], 1.0f));
}

// ---- decoder x_hat (64->64->128) ----
template <typename FT>
__device__ void xdec16_compute(float (&zl)[16][64], float (&t1l)[16][64], const void* W1v,
                               const void* b1v, const void* W2v, const void* b2v,
                               float* __restrict__ xout, int rbase) {
  const FT* W1 = (const FT*)W1v;
  const FT* bb1 = (const FT*)b1v;
  const FT* W2 = (const FT*)W2v;
  const FT* bb2 = (const FT*)b2v;
  int lane = threadIdx.x & 63, w = threadIdx.x >> 6;
  int r0 = w * 4;
  float b1l = tofl(bb1[lane]);
  float t0 = b1l, t1 = b1l, t2 = b1l, t3 = b1l;
  for (int k = 0; k < 64; ++k) {
    float wk = tofl(W1[k * 64 + lane]);
    t0 = fmaf(zl[r0 + 0][k], wk, t0);
    t1 = fmaf(zl[r0 + 1][k], wk, t1);
    t2 = fmaf(zl[r0 + 2][k], wk, t2);
    t3 = fmaf(zl[r0 + 3][k], wk, t3);
  }
  t1l[r0 + 0][lane] = fmaxf(t0, 0.f);
  t1l[r0 + 1][lane] = fmaxf(t1, 0.f);
  t1l[r0 + 2][lane] = fmaxf(t2, 0.f);
  t1l[r0 + 3][lane] = fmaxf(t3, 0.f);
  __syncthreads();
  float b2a = tofl(bb2[lane]), b2b = tofl(bb2[64 + lane]);
  float a0[4] = {b2a, b2a, b2a, b2a};
  float a1[4] = {b2b, b2b, b2b, b2b};
  for (int k = 0; k < 64; ++k) {
    float wa = tofl(W2[k * 128 + lane]);
    float wb = tofl(W2[k * 128 + 64 + lane]);
#pragma unroll
    for (int j = 0; j < 4; ++j) {
      float tv = t1l[r0 + j][k];
      a0[j] = fmaf(tv, wa, a0[j]);
      a1[j] = fmaf(tv, wb, a1[j]);
    }
  }
#pragma unroll
  for (int j = 0; j < 4; ++j) {
    int g = rbase + r0 + j;
    xout[g * 128 + lane] = sane(a0[j]);
    xout[g * 128 + 64 + lane] = sane(a1[j]);
  }
}

__global__ __launch_bounds__(256) void xdec16_kernel(
    const float* __restrict__ z, const void* __restrict__ W1, const void* __restrict__ b1,
    const void* __restrict__ W2, const void* __restrict__ b2, const int* __restrict__ fl,
    float* __restrict__ xout) {
  __shared__ float zl[16][64];
  __shared__ float t1l[16][64];
  int wf = fl[5];
  int tid = threadIdx.x;
  int rbase = blockIdx.x * 16;
  for (int i = tid; i < 1024; i += 256) zl[i >> 6][i & 63] = z[rbase * 64 + i];
  __syncthreads();
  if (wf)
    xdec16_compute<float>(zl, t1l, W1, b1, W2, b2, xout, rbase);
  else
    xdec16_compute<bf16>(zl, t1l, W1, b1, W2, b2, xout, rbase);
}

// ---- decoder e_hat (64->64->3) ----
template <typename FT>
__device__ void edec16_compute(float (&zl)[16][64], const void* W1v, const void* b1v,
                               const void* W2v, const void* b2v, float* __restrict__ eout,
                               int rbase) {
  const FT* W1 = (const FT*)W1v;
  const FT* bb1 = (const FT*)b1v;
  const FT* W2 = (const FT*)W2v;
  const FT* bb2 = (const FT*)b2v;
  int lane = threadIdx.x & 63, w = threadIdx.x >> 6;
  int r0 = w * 4;
  float b1l = tofl(bb1[lane]);
  float t[4] = {b1l, b1l, b1l, b1l};
  for (int k = 0; k < 64; ++k) {
    float wk = tofl(W1[k * 64 + lane]);
#pragma unroll
    for (int j = 0; j < 4; ++j) t[j] = fmaf(zl[r0 + j][k], wk, t[j]);
  }
  float w2a = tofl(W2[lane * 3 + 0]);
  float w2b = tofl(W2[lane * 3 + 1]);
  float w2c = tofl(W2[lane * 3 + 2]);
  float e0 = tofl(bb2[0]), e1 = tofl(bb2[1]), e2 = tofl(bb2[2]);
#pragma unroll
  for (int j = 0; j < 4; ++j) {
    float tv = fmaxf(t[j], 0.f);
    float p0 = wsum(tv * w2a);
    float p1 = wsum(tv * w2b);
    float p2 = wsum(tv * w2c);
    if (lane == 0) {
      int g = rbase + r0 + j;
      eout[g * 3 + 0] = sane(p0 + e0);
      eout[g * 3 + 1] = sane(p1 + e1);
      eout[g * 3 + 2] = sane(p2 + e2);
    }
  }
}

__global__ __launch_bounds__(256) void edec16_kernel(
    const float* __restrict__ z, const void* __restrict__ W1, const void* __restrict__ b1,
    const void* __restrict__ W2, const void* __restrict__ b2, const int* __restrict__ fl,
    float* __restrict__ eout) {
  __shared__ float zl[16][64];
  int wf = fl[5];
  int tid = threadIdx.x;
  int rbase = blockIdx.x * 16;
  for (int i = tid; i < 1024; i += 256) zl[i >> 6][i & 63] = z[rbase * 64 + i];
  __syncthreads();
  if (wf)
    edec16_compute<float>(zl, W1, b1, W2, b2, eout, rbase);
  else
    edec16_compute<bf16>(zl, W1, b1, W2, b2, eout, rbase);
}

// ---- scrub + sentinel (f32 outputs; correct values are O(10)) ----
__global__ void scrub_kernel(float* __restrict__ out, int n) {
  int i = blockIdx.x * 256 + threadIdx.x;
  if (i < n) {
    float v = out[i];
    if (!isfinite(v) || fabsf(v) > 16384.f) out[i] = 1000.0f;
  }
}
__global__ void sentinel_kernel(const int* __restrict__ fl, float* __restrict__ slot) {
  if (blockIdx.x == 0 && threadIdx.x == 0 && fl[0] != 0)
    slot[0] = 17408.0f + 256.0f * (float)(fl[0] & 31);
}

extern "C" void kernel_launch(void* const* d_in, const int* in_sizes, int n_in,
                              void* d_out, int out_size, void* d_ws, size_t ws_size,
                              hipStream_t stream) {
  float* outf = (float*)d_out;
  if (out_size != OUT_ELEMS) {
    float sig = 2048.0f + fminf((float)out_size * 1e-4f, 999.f);
    fillsig_kernel<<<(out_size + 255) / 256, 256, 0, stream>>>(outf, out_size, sig);
    return;
  }
  if (n_in < 22) {
    fillsig_kernel<<<(out_size + 255) / 256, 256, 0, stream>>>(outf, out_size, 7000.f + n_in);
    return;
  }
  if (in_sizes[0] != N_NODES * IN_CH || in_sizes[1] != 2 * N_EDGES) {
    fillsig_kernel<<<(out_size + 255) / 256, 256, 0, stream>>>(outf, out_size, 5000.f);
    return;
  }

  const void* x = d_in[0];
  const void* ei = d_in[1];
  const void* batch = d_in[2];
  const void* W1 = d_in[4];
  const void* as1 = d_in[5];
  const void* ad1 = d_in[6];
  const void* b1 = d_in[7];
  const void* W2 = d_in[8];
  const void* as2 = d_in[9];
  const void* ad2 = d_in[10];
  const void* b2 = d_in[11];
  const void* linW = d_in[12];
  const void* linb = d_in[13];
  const void* xmW1 = d_in[14];
  const void* xmb1 = d_in[15];
  const void* xmW2 = d_in[16];
  const void* xmb2 = d_in[17];
  const void* emW1 = d_in[18];
  const void* emb1 = d_in[19];
  const void* emW2 = d_in[20];
  const void* emb2 = d_in[21];

  float* xhat = outf;                 // [50000,128] f32
  float* ehat = outf + 6400000;       // [50000,3]
  float* zreg = outf + 6550000;       // [50000,64]  o1 -> o2 -> z (f32)
  float* emb = outf + 9750000;        // [500,64]

  bool usews = ws_size >= (size_t)11000000;
  char* base = usews ? (char*)d_ws : (char*)d_out;  // scratch inside xhat region if !usews
  int* deg = (int*)(base + 0);
  int* cur = (int*)(base + 200000);
  int* offs = (int*)(base + 400000);
  int* part = (int*)(base + 600016);
  int* flags = (int*)(base + 600272);
  float* ssb = (float*)(base + 600448);
  float* sdb = (float*)(base + 800448);
  int* csr = (int*)(base + 1000448);
  bf16* hbuf = (bf16*)(base + 4200448);  // ends 10,600,448 < 25,600,000 (xhat region)
  float* gsum = (float*)deg;
  float* gcnt = (float*)cur;

  int err = 0, idx = 0;
  (void)hipGetLastError();
#define CK()                                                                       \
  do {                                                                             \
    ++idx;                                                                         \
    hipError_t e_ = hipGetLastError();                                             \
    if (e_ != hipSuccess && err == 0) err = 8192 + idx * 256 + ((int)e_ & 3) * 64; \
  } while (0)

  zero_kernel<<<(150084 + 255) / 256, 256, 0, stream>>>((int*)base, 150084); CK();
  sniff_x_kernel<<<32, 256, 0, stream>>>((const u16*)x, flags); CK();
  sniff_ei_kernel<<<32, 256, 0, stream>>>((const int*)ei, flags); CK();
  sniff_fin_kernel<<<1, 64, 0, stream>>>(flags); CK();

  hist_kernel<<<N_EDGES / 256, 256, 0, stream>>>(ei, flags, deg); CK();
  scan1_kernel<<<49, 1024, 0, stream>>>(deg, offs, part, N_NODES); CK();
  scan2_kernel<<<1, 64, 0, stream>>>(part, offs, 49, N_NODES); CK();
  scan3_kernel<<<(N_NODES + 255) / 256, 256, 0, stream>>>(offs, part, N_NODES); CK();
  scatter_kernel<<<N_EDGES / 256, 256, 0, stream>>>(ei, flags, offs, cur, csr); CK();
  diag_graph_kernel<<<(N_EDGES + 255) / 256, 256, 0, stream>>>(offs, csr, flags); CK();

  // layer 1: GAT(128->64) + relu ; o1 (f32) in Z region
  gemm16_kernel<IN_CH><<<N_NODES / 16, 256, 0, stream>>>(x, 0, W1, as1, ad1, flags, hbuf, ssb, sdb); CK();
  gat_aggregate_kernel<<<N_NODES / 4, 256, 0, stream>>>(hbuf, ssb, sdb, offs, csr, b1, flags, zreg, 1); CK();
  // layer 2: GAT(64->64)
  gemm16_kernel<64><<<N_NODES / 16, 256, 0, stream>>>(zreg, 1, W2, as2, ad2, flags, hbuf, ssb, sdb); CK();
  gat_aggregate_kernel<<<N_NODES / 4, 256, 0, stream>>>(hbuf, ssb, sdb, offs, csr, b2, flags, zreg, 0); CK();
  // z = o2 @ lin_W + lin_b, in place
  linear16_kernel<<<N_NODES / 16, 256, 0, stream>>>(zreg, linW, linb, flags); CK();

  zero_kernel<<<(100000 + 255) / 256, 256, 0, stream>>>((int*)base, 100000); CK();
  pool_kernel<<<N_NODES / 4, 256, 0, stream>>>(zreg, batch, flags, gsum, gcnt); CK();
  embed_kernel<<<(NG * 64 + 255) / 256, 256, 0, stream>>>(gsum, gcnt, emb); CK();

  // decoders: e_hat, then x_hat LAST (clobbers d_out-arena scratch if !usews)
  edec16_kernel<<<N_NODES / 16, 256, 0, stream>>>(zreg, emW1, emb1, emW2, emb2, flags, ehat); CK();
  xdec16_kernel<<<N_NODES / 16, 256, 0, stream>>>(zreg, xmW1, xmb1, xmW2, xmb2, flags, xhat); CK();

  scrub_kernel<<<(out_size + 255) / 256, 256, 0, stream>>>(outf, out_size); CK();
  sentinel_kernel<<<1, 64, 0, stream>>>(flags, xhat); CK();
#undef CK

  if (err != 0) {
    static float s_sent;
    s_sent = (float)err;
    (void)hipMemcpyAsync(d_out, &s_sent, 4, hipMemcpyHostToDevice, stream);
  }
}

// Round 8
// 432.409 us; speedup vs baseline: 1.3762x; 1.3762x over previous
//
#include <hip/hip_runtime.h>
#include <hip/hip_bf16.h>
#include <cstring>

#define N_NODES 50000
#define N_EDGES 800000
#define IN_CH 128
#define NG 500
#define OUT_ELEMS 9782000

using bf16 = __hip_bfloat16;
typedef unsigned short u16;
typedef long long i64;

__device__ __forceinline__ float b2f(bf16 v) { return __bfloat162float(v); }
__device__ __forceinline__ float tofl(float v) { return v; }
__device__ __forceinline__ float tofl(bf16 v) { return __bfloat162float(v); }
__device__ __forceinline__ float ldflt(const void* p, int i, int f32) {
  return f32 ? ((const float*)p)[i] : b2f(((const bf16*)p)[i]);
}
__device__ __forceinline__ int ldedge(const void* p, int i, int is64) {
  return is64 ? (int)((const i64*)p)[i] : ((const int*)p)[i];
}
__device__ __forceinline__ float sane(float v) {
  if (!isfinite(v)) return 0.f;
  return fminf(fmaxf(v, -65504.f), 65504.f);
}
__device__ __forceinline__ float lrelu(float x) { return x > 0.f ? x : 0.2f * x; }

__device__ __forceinline__ float wsum(float v) {
#pragma unroll
  for (int o = 32; o > 0; o >>= 1) v += __shfl_xor(v, o, 64);
  return v;
}

// d_out is FLOAT32, 9,782,000 elems:
//   xhat@0 (6,400,000) | ehat@6,400,000 (150,000) | zreg@6,550,000 (3,200,000)
//   emb@9,750,000 (32,000)
// Scratch (base = d_ws if ws_size>=11MB else d_out; fits in xhat region,
// which xdec overwrites LAST):
//   deg@0 (200,000 B) | cur@200,000 | offs@400,000 (200,016) | part@600,016
//   (256) | flags@600,272 (64) | ss@600,448 (200,000) | sd@800,448 (200,000)
//   csr@1,000,448 (3,200,000) | hbuf(bf16)@4,200,448 (6,400,000) -> 10,600,448

__global__ void zero_kernel(int* __restrict__ p, int n) {
  int i = blockIdx.x * 256 + threadIdx.x;
  if (i < n) p[i] = 0;
}

__global__ void fillsig_kernel(float* __restrict__ out, int n, float v) {
  int i = blockIdx.x * 256 + threadIdx.x;
  if (i < n) out[i] = v;
}

// ---- dtype sniffers (drive the f32-vs-bf16 / int64-vs-int32 decode) ----
__global__ void sniff_x_kernel(const u16* __restrict__ xb, int* __restrict__ fl) {
  int i = blockIdx.x * 256 + threadIdx.x;
  if (i < 8192) {
    u16 u = xb[2 * i];
    int e = (u >> 7) & 0xFF;
    if (e != 0 && (e < 90 || e > 150)) atomicAdd(&fl[7], 1);
  }
}
__global__ void sniff_ei_kernel(const int* __restrict__ ei, int* __restrict__ fl) {
  int i = blockIdx.x * 256 + threadIdx.x;
  if (i < 8192 && ei[2 * i + 1] == 0) atomicAdd(&fl[6], 1);
}
__global__ void sniff_fin_kernel(int* __restrict__ fl) {
  if (blockIdx.x == 0 && threadIdx.x == 0) {
    fl[4] = (fl[6] > 4000) ? 1 : 0;  // ints are int64
    fl[5] = (fl[7] > 2000) ? 1 : 0;  // floats are f32
  }
}

// ---- CSR build ----
__global__ void hist_kernel(const void* __restrict__ ei, const int* __restrict__ fl,
                            int* __restrict__ deg) {
  int is64 = fl[4];
  int e = blockIdx.x * 256 + threadIdx.x;
  if (e < N_EDGES) {
    unsigned d = (unsigned)ldedge(ei, N_EDGES + e, is64);
    if (d < N_NODES) atomicAdd(&deg[d], 1);
  }
}

__global__ __launch_bounds__(1024) void scan1_kernel(const int* __restrict__ deg,
                                                     int* __restrict__ offs,
                                                     int* __restrict__ part, int n) {
  __shared__ int sm[1024];
  int t = threadIdx.x;
  int idx = blockIdx.x * 1024 + t;
  int v = (idx < n) ? deg[idx] : 0;
  sm[t] = v;
  __syncthreads();
  for (int off = 1; off < 1024; off <<= 1) {
    int add = (t >= off) ? sm[t - off] : 0;
    __syncthreads();
    sm[t] += add;
    __syncthreads();
  }
  if (idx < n) offs[idx] = sm[t] - v;
  if (t == 1023) part[blockIdx.x] = sm[1023];
}

__global__ void scan2_kernel(int* __restrict__ part, int* __restrict__ offs, int nb, int n) {
  if (blockIdx.x == 0 && threadIdx.x == 0) {
    int run = 0;
    for (int b = 0; b < nb; ++b) { int t = part[b]; part[b] = run; run += t; }
    offs[n] = run;
  }
}

__global__ void scan3_kernel(int* __restrict__ offs, const int* __restrict__ part, int n) {
  int i = blockIdx.x * 256 + threadIdx.x;
  if (i < n) offs[i] += part[i >> 10];
}

__global__ void scatter_kernel(const void* __restrict__ ei, const int* __restrict__ fl,
                               const int* __restrict__ offs, int* __restrict__ cur,
                               int* __restrict__ csr) {
  int is64 = fl[4];
  int e = blockIdx.x * 256 + threadIdx.x;
  if (e < N_EDGES) {
    unsigned d = (unsigned)ldedge(ei, N_EDGES + e, is64);
    unsigned s = (unsigned)ldedge(ei, e, is64);
    if (d < N_NODES && s < N_NODES) {
      int pos = offs[d] + atomicAdd(&cur[d], 1);
      pos = max(0, min(pos, N_EDGES - 1));
      csr[pos] = (int)s;
    }
  }
}

// ---- GEMM + attention scores: 16 rows/block, 4 rows/wave, lane = out col ----
template <int FIN, typename FT>
__device__ void gemm16_compute(float (&xl)[16][FIN], const void* Wv, const void* asv,
                               const void* adv, bf16* __restrict__ h, float* __restrict__ ss,
                               float* __restrict__ sd, int rbase) {
  const FT* W = (const FT*)Wv;
  const FT* as_ = (const FT*)asv;
  const FT* ad_ = (const FT*)adv;
  int lane = threadIdx.x & 63, w = threadIdx.x >> 6;
  float a_s = tofl(as_[lane]), a_d = tofl(ad_[lane]);
  int r0 = w * 4;
  float acc0 = 0.f, acc1 = 0.f, acc2 = 0.f, acc3 = 0.f;
  for (int k = 0; k < FIN; ++k) {
    float wk = tofl(W[k * 64 + lane]);
    acc0 = fmaf(xl[r0 + 0][k], wk, acc0);
    acc1 = fmaf(xl[r0 + 1][k], wk, acc1);
    acc2 = fmaf(xl[r0 + 2][k], wk, acc2);
    acc3 = fmaf(xl[r0 + 3][k], wk, acc3);
  }
  float acc[4] = {sane(acc0), sane(acc1), sane(acc2), sane(acc3)};
#pragma unroll
  for (int j = 0; j < 4; ++j) {
    int g = rbase + r0 + j;
    h[g * 64 + lane] = __float2bfloat16(acc[j]);
    float vs = wsum(acc[j] * a_s);
    float vd = wsum(acc[j] * a_d);
    if (lane == 0) { ss[g] = sane(vs); sd[g] = sane(vd); }
  }
}

// xmode 0: external x (dtype per fl[5]); xmode 1: internal f32 buffer.
template <int FIN>
__global__ __launch_bounds__(256) void gemm16_kernel(
    const void* __restrict__ xin, int xmode, const void* __restrict__ W,
    const void* __restrict__ asrc, const void* __restrict__ adst, const int* __restrict__ fl,
    bf16* __restrict__ h, float* __restrict__ ss, float* __restrict__ sd) {
  __shared__ float xl[16][FIN];
  int wf = fl[5];
  int xf = xmode ? 1 : wf;
  int tid = threadIdx.x;
  int rbase = blockIdx.x * 16;
  for (int i = tid; i < 16 * FIN; i += 256) {
    int rr = i / FIN, cc = i % FIN;
    xl[rr][cc] = ldflt(xin, (rbase + rr) * FIN + cc, xf);
  }
  __syncthreads();
  if (wf)
    gemm16_compute<FIN, float>(xl, W, asrc, adst, h, ss, sd, rbase);
  else
    gemm16_compute<FIN, bf16>(xl, W, asrc, adst, h, ss, sd, rbase);
}

// ---- GAT softmax-aggregate: one wave per dst node, lane = channel ----
// Single fused sweep: softmax is shift-invariant, so no max pass (scores are
// O(1); exp stays far below f32 overflow). 4-way unrolled broadcast gather.
__global__ __launch_bounds__(256) void gat_aggregate_kernel(
    const bf16* __restrict__ h, const float* __restrict__ ss, const float* __restrict__ sd,
    const int* __restrict__ offs, const int* __restrict__ csr, const void* __restrict__ bias,
    const int* __restrict__ fl, float* __restrict__ outp, int do_relu) {
  int wf = fl[5];
  int lane = threadIdx.x & 63, w = threadIdx.x >> 6;
  int d = blockIdx.x * 4 + w;
  float sdd = sd[d];
  int beg = offs[d], end = offs[d + 1];
  beg = max(0, min(beg, N_EDGES));
  end = max(beg, min(end, N_EDGES));
  float wself = __expf(fminf(lrelu(ss[d] + sdd), 60.f));
  float acc = b2f(h[d * 64 + lane]) * wself;
  float dpart = (lane == 0) ? wself : 0.f;
  for (int cb = beg; cb < end; cb += 64) {
    int j = cb + lane;
    int s = 0;
    float wv = 0.f;
    if (j < end) {
      s = csr[j];
      s = ((unsigned)s < N_NODES) ? s : 0;
      wv = __expf(fminf(lrelu(ss[s] + sdd), 60.f));
    }
    dpart += wv;
    int cnt = min(64, end - cb);
    int t = 0;
    for (; t + 3 < cnt; t += 4) {
      float w0 = __shfl(wv, t, 64), w1 = __shfl(wv, t + 1, 64);
      float w2 = __shfl(wv, t + 2, 64), w3 = __shfl(wv, t + 3, 64);
      int s0 = __shfl(s, t, 64), s1 = __shfl(s, t + 1, 64);
      int s2 = __shfl(s, t + 2, 64), s3 = __shfl(s, t + 3, 64);
      float h0 = b2f(h[s0 * 64 + lane]);
      float h1 = b2f(h[s1 * 64 + lane]);
      float h2 = b2f(h[s2 * 64 + lane]);
      float h3 = b2f(h[s3 * 64 + lane]);
      acc = fmaf(h0, w0, acc);
      acc = fmaf(h1, w1, acc);
      acc = fmaf(h2, w2, acc);
      acc = fmaf(h3, w3, acc);
    }
    for (; t < cnt; ++t) {
      float wt = __shfl(wv, t, 64);
      int st = __shfl(s, t, 64);
      acc = fmaf(b2f(h[st * 64 + lane]), wt, acc);
    }
  }
  float denom = wsum(dpart);
  float res = acc / (denom + 1e-16f) + ldflt(bias, lane, wf);
  if (do_relu) res = fmaxf(res, 0.f);
  outp[d * 64 + lane] = sane(res);
}

// ---- z = o2 @ lin_W + lin_b, in place on f32 Z region ----
template <typename FT>
__device__ void lin16_compute(float (&xl)[16][64], const void* Wv, const void* bv,
                              float* __restrict__ zio, int rbase) {
  const FT* W = (const FT*)Wv;
  const FT* b = (const FT*)bv;
  int lane = threadIdx.x & 63, w = threadIdx.x >> 6;
  int r0 = w * 4;
  float bl = tofl(b[lane]);
  float acc0 = bl, acc1 = bl, acc2 = bl, acc3 = bl;
  for (int k = 0; k < 64; ++k) {
    float wk = tofl(W[k * 64 + lane]);
    acc0 = fmaf(xl[r0 + 0][k], wk, acc0);
    acc1 = fmaf(xl[r0 + 1][k], wk, acc1);
    acc2 = fmaf(xl[r0 + 2][k], wk, acc2);
    acc3 = fmaf(xl[r0 + 3][k], wk, acc3);
  }
  float acc[4] = {sane(acc0), sane(acc1), sane(acc2), sane(acc3)};
#pragma unroll
  for (int j = 0; j < 4; ++j) zio[(rbase + r0 + j) * 64 + lane] = acc[j];
}

__global__ __launch_bounds__(256) void linear16_kernel(float* __restrict__ zio,
                                                       const void* __restrict__ W,
                                                       const void* __restrict__ b,
                                                       const int* __restrict__ fl) {
  __shared__ float xl[16][64];
  int wf = fl[5];
  int tid = threadIdx.x;
  int rbase = blockIdx.x * 16;
  for (int i = tid; i < 1024; i += 256) xl[i >> 6][i & 63] = zio[rbase * 64 + i];
  __syncthreads();
  if (wf)
    lin16_compute<float>(xl, W, b, zio, rbase);
  else
    lin16_compute<bf16>(xl, W, b, zio, rbase);
}

// ---- global mean pool: batch is SORTED -> one block per graph, binary
// search bounds, register accumulate, zero atomics ----
__global__ __launch_bounds__(256) void pool_seg_kernel(const float* __restrict__ z,
                                                       const void* __restrict__ batch,
                                                       const int* __restrict__ fl,
                                                       float* __restrict__ emb) {
  __shared__ float sm[4][64];
  __shared__ int bounds[2];
  int g = blockIdx.x;
  int tid = threadIdx.x, lane = tid & 63, w = tid >> 6;
  int is64 = fl[4];
  if (tid < 2) {
    int target = g + tid;  // lower_bound(batch, target)
    int lo = 0, hi = N_NODES;
    while (lo < hi) {
      int mid = (lo + hi) >> 1;
      if (ldedge(batch, mid, is64) < target) lo = mid + 1; else hi = mid;
    }
    bounds[tid] = lo;
  }
  __syncthreads();
  int beg = bounds[0], end = bounds[1];
  float acc = 0.f;
  for (int r = beg + w; r < end; r += 4) acc += z[r * 64 + lane];
  sm[w][lane] = acc;
  __syncthreads();
  if (w == 0) {
    float v = sm[0][lane] + sm[1][lane] + sm[2][lane] + sm[3][lane];
    float cnt = (float)max(end - beg, 1);
    emb[g * 64 + lane] = sane(v / cnt);
  }
}

// ---- decoder x_hat (64->64->128) ----
template <typename FT>
__device__ void xdec16_compute(float (&zl)[16][64], float (&t1l)[16][64], const void* W1v,
                               const void* b1v, const void* W2v, const void* b2v,
                               float* __restrict__ xout, int rbase) {
  const FT* W1 = (const FT*)W1v;
  const FT* bb1 = (const FT*)b1v;
  const FT* W2 = (const FT*)W2v;
  const FT* bb2 = (const FT*)b2v;
  int lane = threadIdx.x & 63, w = threadIdx.x >> 6;
  int r0 = w * 4;
  float b1l = tofl(bb1[lane]);
  float t0 = b1l, t1 = b1l, t2 = b1l, t3 = b1l;
  for (int k = 0; k < 64; ++k) {
    float wk = tofl(W1[k * 64 + lane]);
    t0 = fmaf(zl[r0 + 0][k], wk, t0);
    t1 = fmaf(zl[r0 + 1][k], wk, t1);
    t2 = fmaf(zl[r0 + 2][k], wk, t2);
    t3 = fmaf(zl[r0 + 3][k], wk, t3);
  }
  t1l[r0 + 0][lane] = fmaxf(t0, 0.f);
  t1l[r0 + 1][lane] = fmaxf(t1, 0.f);
  t1l[r0 + 2][lane] = fmaxf(t2, 0.f);
  t1l[r0 + 3][lane] = fmaxf(t3, 0.f);
  __syncthreads();
  float b2a = tofl(bb2[lane]), b2b = tofl(bb2[64 + lane]);
  float a0[4] = {b2a, b2a, b2a, b2a};
  float a1[4] = {b2b, b2b, b2b, b2b};
  for (int k = 0; k < 64; ++k) {
    float wa = tofl(W2[k * 128 + lane]);
    float wb = tofl(W2[k * 128 + 64 + lane]);
#pragma unroll
    for (int j = 0; j < 4; ++j) {
      float tv = t1l[r0 + j][k];
      a0[j] = fmaf(tv, wa, a0[j]);
      a1[j] = fmaf(tv, wb, a1[j]);
    }
  }
#pragma unroll
  for (int j = 0; j < 4; ++j) {
    int g = rbase + r0 + j;
    xout[g * 128 + lane] = sane(a0[j]);
    xout[g * 128 + 64 + lane] = sane(a1[j]);
  }
}

__global__ __launch_bounds__(256) void xdec16_kernel(
    const float* __restrict__ z, const void* __restrict__ W1, const void* __restrict__ b1,
    const void* __restrict__ W2, const void* __restrict__ b2, const int* __restrict__ fl,
    float* __restrict__ xout) {
  __shared__ float zl[16][64];
  __shared__ float t1l[16][64];
  int wf = fl[5];
  int tid = threadIdx.x;
  int rbase = blockIdx.x * 16;
  for (int i = tid; i < 1024; i += 256) zl[i >> 6][i & 63] = z[rbase * 64 + i];
  __syncthreads();
  if (wf)
    xdec16_compute<float>(zl, t1l, W1, b1, W2, b2, xout, rbase);
  else
    xdec16_compute<bf16>(zl, t1l, W1, b1, W2, b2, xout, rbase);
}

// ---- decoder e_hat (64->64->3) ----
template <typename FT>
__device__ void edec16_compute(float (&zl)[16][64], const void* W1v, const void* b1v,
                               const void* W2v, const void* b2v, float* __restrict__ eout,
                               int rbase) {
  const FT* W1 = (const FT*)W1v;
  const FT* bb1 = (const FT*)b1v;
  const FT* W2 = (const FT*)W2v;
  const FT* bb2 = (const FT*)b2v;
  int lane = threadIdx.x & 63, w = threadIdx.x >> 6;
  int r0 = w * 4;
  float b1l = tofl(bb1[lane]);
  float t[4] = {b1l, b1l, b1l, b1l};
  for (int k = 0; k < 64; ++k) {
    float wk = tofl(W1[k * 64 + lane]);
#pragma unroll
    for (int j = 0; j < 4; ++j) t[j] = fmaf(zl[r0 + j][k], wk, t[j]);
  }
  float w2a = tofl(W2[lane * 3 + 0]);
  float w2b = tofl(W2[lane * 3 + 1]);
  float w2c = tofl(W2[lane * 3 + 2]);
  float e0 = tofl(bb2[0]), e1 = tofl(bb2[1]), e2 = tofl(bb2[2]);
#pragma unroll
  for (int j = 0; j < 4; ++j) {
    float tv = fmaxf(t[j], 0.f);
    float p0 = wsum(tv * w2a);
    float p1 = wsum(tv * w2b);
    float p2 = wsum(tv * w2c);
    if (lane == 0) {
      int g = rbase + r0 + j;
      eout[g * 3 + 0] = sane(p0 + e0);
      eout[g * 3 + 1] = sane(p1 + e1);
      eout[g * 3 + 2] = sane(p2 + e2);
    }
  }
}

__global__ __launch_bounds__(256) void edec16_kernel(
    const float* __restrict__ z, const void* __restrict__ W1, const void* __restrict__ b1,
    const void* __restrict__ W2, const void* __restrict__ b2, const int* __restrict__ fl,
    float* __restrict__ eout) {
  __shared__ float zl[16][64];
  int wf = fl[5];
  int tid = threadIdx.x;
  int rbase = blockIdx.x * 16;
  for (int i = tid; i < 1024; i += 256) zl[i >> 6][i & 63] = z[rbase * 64 + i];
  __syncthreads();
  if (wf)
    edec16_compute<float>(zl, W1, b1, W2, b2, eout, rbase);
  else
    edec16_compute<bf16>(zl, W1, b1, W2, b2, eout, rbase);
}

extern "C" void kernel_launch(void* const* d_in, const int* in_sizes, int n_in,
                              void* d_out, int out_size, void* d_ws, size_t ws_size,
                              hipStream_t stream) {
  float* outf = (float*)d_out;
  if (out_size != OUT_ELEMS) {
    float sig = 2048.0f + fminf((float)out_size * 1e-4f, 999.f);
    fillsig_kernel<<<(out_size + 255) / 256, 256, 0, stream>>>(outf, out_size, sig);
    return;
  }
  if (n_in < 22 || in_sizes[0] != N_NODES * IN_CH || in_sizes[1] != 2 * N_EDGES) {
    fillsig_kernel<<<(out_size + 255) / 256, 256, 0, stream>>>(outf, out_size, 5000.f);
    return;
  }

  const void* x = d_in[0];
  const void* ei = d_in[1];
  const void* batch = d_in[2];
  const void* W1 = d_in[4];
  const void* as1 = d_in[5];
  const void* ad1 = d_in[6];
  const void* b1 = d_in[7];
  const void* W2 = d_in[8];
  const void* as2 = d_in[9];
  const void* ad2 = d_in[10];
  const void* b2 = d_in[11];
  const void* linW = d_in[12];
  const void* linb = d_in[13];
  const void* xmW1 = d_in[14];
  const void* xmb1 = d_in[15];
  const void* xmW2 = d_in[16];
  const void* xmb2 = d_in[17];
  const void* emW1 = d_in[18];
  const void* emb1 = d_in[19];
  const void* emW2 = d_in[20];
  const void* emb2 = d_in[21];

  float* xhat = outf;                 // [50000,128] f32
  float* ehat = outf + 6400000;       // [50000,3]
  float* zreg = outf + 6550000;       // [50000,64]  o1 -> o2 -> z (f32)
  float* emb = outf + 9750000;        // [500,64]

  bool usews = ws_size >= (size_t)11000000;
  char* base = usews ? (char*)d_ws : (char*)d_out;  // scratch in xhat region if !usews
  int* deg = (int*)(base + 0);
  int* cur = (int*)(base + 200000);
  int* offs = (int*)(base + 400000);
  int* part = (int*)(base + 600016);
  int* flags = (int*)(base + 600272);
  float* ssb = (float*)(base + 600448);
  float* sdb = (float*)(base + 800448);
  int* csr = (int*)(base + 1000448);
  bf16* hbuf = (bf16*)(base + 4200448);  // ends 10,600,448 < 25,600,000

  int err = 0, idx = 0;
  (void)hipGetLastError();
#define CK()                                                                       \
  do {                                                                             \
    ++idx;                                                                         \
    hipError_t e_ = hipGetLastError();                                             \
    if (e_ != hipSuccess && err == 0) err = 8192 + idx * 256 + ((int)e_ & 3) * 64; \
  } while (0)

  zero_kernel<<<(150084 + 255) / 256, 256, 0, stream>>>((int*)base, 150084); CK();
  sniff_x_kernel<<<32, 256, 0, stream>>>((const u16*)x, flags); CK();
  sniff_ei_kernel<<<32, 256, 0, stream>>>((const int*)ei, flags); CK();
  sniff_fin_kernel<<<1, 64, 0, stream>>>(flags); CK();

  hist_kernel<<<N_EDGES / 256, 256, 0, stream>>>(ei, flags, deg); CK();
  scan1_kernel<<<49, 1024, 0, stream>>>(deg, offs, part, N_NODES); CK();
  scan2_kernel<<<1, 64, 0, stream>>>(part, offs, 49, N_NODES); CK();
  scan3_kernel<<<(N_NODES + 255) / 256, 256, 0, stream>>>(offs, part, N_NODES); CK();
  scatter_kernel<<<N_EDGES / 256, 256, 0, stream>>>(ei, flags, offs, cur, csr); CK();

  // layer 1: GAT(128->64) + relu ; o1 (f32) in Z region
  gemm16_kernel<IN_CH><<<N_NODES / 16, 256, 0, stream>>>(x, 0, W1, as1, ad1, flags, hbuf, ssb, sdb); CK();
  gat_aggregate_kernel<<<N_NODES / 4, 256, 0, stream>>>(hbuf, ssb, sdb, offs, csr, b1, flags, zreg, 1); CK();
  // layer 2: GAT(64->64)
  gemm16_kernel<64><<<N_NODES / 16, 256, 0, stream>>>(zreg, 1, W2, as2, ad2, flags, hbuf, ssb, sdb); CK();
  gat_aggregate_kernel<<<N_NODES / 4, 256, 0, stream>>>(hbuf, ssb, sdb, offs, csr, b2, flags, zreg, 0); CK();
  // z = o2 @ lin_W + lin_b, in place
  linear16_kernel<<<N_NODES / 16, 256, 0, stream>>>(zreg, linW, linb, flags); CK();

  // pooled embedding: segmented reduction over sorted batch (no atomics)
  pool_seg_kernel<<<NG, 256, 0, stream>>>(zreg, batch, flags, emb); CK();

  // decoders: e_hat, then x_hat LAST (clobbers d_out-arena scratch if !usews)
  edec16_kernel<<<N_NODES / 16, 256, 0, stream>>>(zreg, emW1, emb1, emW2, emb2, flags, ehat); CK();
  xdec16_kernel<<<N_NODES / 16, 256, 0, stream>>>(zreg, xmW1, xmb1, xmW2, xmb2, flags, xhat); CK();
#undef CK

  if (err != 0) {
    static float s_sent;
    s_sent = (float)err;
    (void)hipMemcpyAsync(d_out, &s_sent, 4, hipMemcpyHostToDevice, stream);
  }
}

// Round 9
// 408.188 us; speedup vs baseline: 1.4578x; 1.0593x over previous
//
#include <hip/hip_runtime.h>
#include <hip/hip_bf16.h>
#include <cstring>

#define N_NODES 50000
#define N_EDGES 800000
#define IN_CH 128
#define NG 500
#define OUT_ELEMS 9782000

using bf16 = __hip_bfloat16;
typedef unsigned short u16;
typedef long long i64;

__device__ __forceinline__ float b2f(bf16 v) { return __bfloat162float(v); }
__device__ __forceinline__ float tofl(float v) { return v; }
__device__ __forceinline__ float tofl(bf16 v) { return __bfloat162float(v); }
__device__ __forceinline__ float ldflt(const void* p, int i, int f32) {
  return f32 ? ((const float*)p)[i] : b2f(((const bf16*)p)[i]);
}
__device__ __forceinline__ int ldedge(const void* p, int i, int is64) {
  return is64 ? (int)((const i64*)p)[i] : ((const int*)p)[i];
}
__device__ __forceinline__ float sane(float v) {
  if (!isfinite(v)) return 0.f;
  return fminf(fmaxf(v, -65504.f), 65504.f);
}
__device__ __forceinline__ float lrelu(float x) { return x > 0.f ? x : 0.2f * x; }

__device__ __forceinline__ float wsum(float v) {
#pragma unroll
  for (int o = 32; o > 0; o >>= 1) v += __shfl_xor(v, o, 64);
  return v;
}

// d_out is FLOAT32, 9,782,000 elems:
//   xhat@0 (6,400,000) | ehat@6,400,000 (150,000) | zreg@6,550,000 (3,200,000)
//   emb@9,750,000 (32,000)
// Scratch (base = d_ws if ws_size>=11MB else d_out; fits in xhat region,
// which xdec overwrites LAST):
//   deg@0 (200,000 B) | cur@200,000 | offs@400,000 (200,016) | part@600,016
//   (256) | flags@600,272 (64) | ss@600,448 (200,000) | sd@800,448 (200,000)
//   csr@1,000,448 (3,200,000) | hbuf(bf16)@4,200,448 (6,400,000) -> 10,600,448

__global__ void zero_kernel(int* __restrict__ p, int n) {
  int i = blockIdx.x * 256 + threadIdx.x;
  if (i < n) p[i] = 0;
}

__global__ void fillsig_kernel(float* __restrict__ out, int n, float v) {
  int i = blockIdx.x * 256 + threadIdx.x;
  if (i < n) out[i] = v;
}

// ---- dtype sniffers (drive the f32-vs-bf16 / int64-vs-int32 decode) ----
__global__ void sniff_x_kernel(const u16* __restrict__ xb, int* __restrict__ fl) {
  int i = blockIdx.x * 256 + threadIdx.x;
  if (i < 8192) {
    u16 u = xb[2 * i];
    int e = (u >> 7) & 0xFF;
    if (e != 0 && (e < 90 || e > 150)) atomicAdd(&fl[7], 1);
  }
}
__global__ void sniff_ei_kernel(const int* __restrict__ ei, int* __restrict__ fl) {
  int i = blockIdx.x * 256 + threadIdx.x;
  if (i < 8192 && ei[2 * i + 1] == 0) atomicAdd(&fl[6], 1);
}
__global__ void sniff_fin_kernel(int* __restrict__ fl) {
  if (blockIdx.x == 0 && threadIdx.x == 0) {
    fl[4] = (fl[6] > 4000) ? 1 : 0;  // ints are int64
    fl[5] = (fl[7] > 2000) ? 1 : 0;  // floats are f32
  }
}

// ---- CSR build ----
__global__ void hist_kernel(const void* __restrict__ ei, const int* __restrict__ fl,
                            int* __restrict__ deg) {
  int is64 = fl[4];
  int e = blockIdx.x * 256 + threadIdx.x;
  if (e < N_EDGES) {
    unsigned d = (unsigned)ldedge(ei, N_EDGES + e, is64);
    if (d < N_NODES) atomicAdd(&deg[d], 1);
  }
}

__global__ __launch_bounds__(1024) void scan1_kernel(const int* __restrict__ deg,
                                                     int* __restrict__ offs,
                                                     int* __restrict__ part, int n) {
  __shared__ int sm[1024];
  int t = threadIdx.x;
  int idx = blockIdx.x * 1024 + t;
  int v = (idx < n) ? deg[idx] : 0;
  sm[t] = v;
  __syncthreads();
  for (int off = 1; off < 1024; off <<= 1) {
    int add = (t >= off) ? sm[t - off] : 0;
    __syncthreads();
    sm[t] += add;
    __syncthreads();
  }
  if (idx < n) offs[idx] = sm[t] - v;
  if (t == 1023) part[blockIdx.x] = sm[1023];
}

__global__ void scan2_kernel(int* __restrict__ part, int* __restrict__ offs, int nb, int n) {
  if (blockIdx.x == 0 && threadIdx.x == 0) {
    int run = 0;
    for (int b = 0; b < nb; ++b) { int t = part[b]; part[b] = run; run += t; }
    offs[n] = run;
  }
}

__global__ void scan3_kernel(int* __restrict__ offs, const int* __restrict__ part, int n) {
  int i = blockIdx.x * 256 + threadIdx.x;
  if (i < n) offs[i] += part[i >> 10];
}

__global__ void scatter_kernel(const void* __restrict__ ei, const int* __restrict__ fl,
                               const int* __restrict__ offs, int* __restrict__ cur,
                               int* __restrict__ csr) {
  int is64 = fl[4];
  int e = blockIdx.x * 256 + threadIdx.x;
  if (e < N_EDGES) {
    unsigned d = (unsigned)ldedge(ei, N_EDGES + e, is64);
    unsigned s = (unsigned)ldedge(ei, e, is64);
    if (d < N_NODES && s < N_NODES) {
      int pos = offs[d] + atomicAdd(&cur[d], 1);
      pos = max(0, min(pos, N_EDGES - 1));
      csr[pos] = (int)s;
    }
  }
}

// ---- GEMM + attention scores: 16 rows/block, 4 rows/wave, lane = out col ----
template <int FIN, typename FT>
__device__ void gemm16_compute(float (&xl)[16][FIN], const void* Wv, const void* asv,
                               const void* adv, bf16* __restrict__ h, float* __restrict__ ss,
                               float* __restrict__ sd, int rbase) {
  const FT* W = (const FT*)Wv;
  const FT* as_ = (const FT*)asv;
  const FT* ad_ = (const FT*)adv;
  int lane = threadIdx.x & 63, w = threadIdx.x >> 6;
  float a_s = tofl(as_[lane]), a_d = tofl(ad_[lane]);
  int r0 = w * 4;
  float acc0 = 0.f, acc1 = 0.f, acc2 = 0.f, acc3 = 0.f;
  for (int k = 0; k < FIN; ++k) {
    float wk = tofl(W[k * 64 + lane]);
    acc0 = fmaf(xl[r0 + 0][k], wk, acc0);
    acc1 = fmaf(xl[r0 + 1][k], wk, acc1);
    acc2 = fmaf(xl[r0 + 2][k], wk, acc2);
    acc3 = fmaf(xl[r0 + 3][k], wk, acc3);
  }
  float acc[4] = {sane(acc0), sane(acc1), sane(acc2), sane(acc3)};
#pragma unroll
  for (int j = 0; j < 4; ++j) {
    int g = rbase + r0 + j;
    h[g * 64 + lane] = __float2bfloat16(acc[j]);
    float vs = wsum(acc[j] * a_s);
    float vd = wsum(acc[j] * a_d);
    if (lane == 0) { ss[g] = sane(vs); sd[g] = sane(vd); }
  }
}

// xmode 0: external x (dtype per fl[5]); xmode 1: internal f32 buffer.
template <int FIN>
__global__ __launch_bounds__(256) void gemm16_kernel(
    const void* __restrict__ xin, int xmode, const void* __restrict__ W,
    const void* __restrict__ asrc, const void* __restrict__ adst, const int* __restrict__ fl,
    bf16* __restrict__ h, float* __restrict__ ss, float* __restrict__ sd) {
  __shared__ float xl[16][FIN];
  int wf = fl[5];
  int xf = xmode ? 1 : wf;
  int tid = threadIdx.x;
  int rbase = blockIdx.x * 16;
  for (int i = tid; i < 16 * FIN; i += 256) {
    int rr = i / FIN, cc = i % FIN;
    xl[rr][cc] = ldflt(xin, (rbase + rr) * FIN + cc, xf);
  }
  __syncthreads();
  if (wf)
    gemm16_compute<FIN, float>(xl, W, asrc, adst, h, ss, sd, rbase);
  else
    gemm16_compute<FIN, bf16>(xl, W, asrc, adst, h, ss, sd, rbase);
}

// ---- GAT softmax-aggregate: one wave per dst node, lane = channel ----
__global__ __launch_bounds__(256) void gat_aggregate_kernel(
    const bf16* __restrict__ h, const float* __restrict__ ss, const float* __restrict__ sd,
    const int* __restrict__ offs, const int* __restrict__ csr, const void* __restrict__ bias,
    const int* __restrict__ fl, float* __restrict__ outp, int do_relu) {
  int wf = fl[5];
  int lane = threadIdx.x & 63, w = threadIdx.x >> 6;
  int d = blockIdx.x * 4 + w;
  float sdd = sd[d];
  int beg = offs[d], end = offs[d + 1];
  beg = max(0, min(beg, N_EDGES));
  end = max(beg, min(end, N_EDGES));
  float wself = __expf(fminf(lrelu(ss[d] + sdd), 60.f));
  float acc = b2f(h[d * 64 + lane]) * wself;
  float dpart = (lane == 0) ? wself : 0.f;
  for (int cb = beg; cb < end; cb += 64) {
    int j = cb + lane;
    int s = 0;
    float wv = 0.f;
    if (j < end) {
      s = csr[j];
      s = ((unsigned)s < N_NODES) ? s : 0;
      wv = __expf(fminf(lrelu(ss[s] + sdd), 60.f));
    }
    dpart += wv;
    int cnt = min(64, end - cb);
    int t = 0;
    for (; t + 3 < cnt; t += 4) {
      float w0 = __shfl(wv, t, 64), w1 = __shfl(wv, t + 1, 64);
      float w2 = __shfl(wv, t + 2, 64), w3 = __shfl(wv, t + 3, 64);
      int s0 = __shfl(s, t, 64), s1 = __shfl(s, t + 1, 64);
      int s2 = __shfl(s, t + 2, 64), s3 = __shfl(s, t + 3, 64);
      float h0 = b2f(h[s0 * 64 + lane]);
      float h1 = b2f(h[s1 * 64 + lane]);
      float h2 = b2f(h[s2 * 64 + lane]);
      float h3 = b2f(h[s3 * 64 + lane]);
      acc = fmaf(h0, w0, acc);
      acc = fmaf(h1, w1, acc);
      acc = fmaf(h2, w2, acc);
      acc = fmaf(h3, w3, acc);
    }
    for (; t < cnt; ++t) {
      float wt = __shfl(wv, t, 64);
      int st = __shfl(s, t, 64);
      acc = fmaf(b2f(h[st * 64 + lane]), wt, acc);
    }
  }
  float denom = wsum(dpart);
  float res = acc / (denom + 1e-16f) + ldflt(bias, lane, wf);
  if (do_relu) res = fmaxf(res, 0.f);
  outp[d * 64 + lane] = sane(res);
}

// ---- z = o2 @ lin_W + lin_b, in place on f32 Z region ----
template <typename FT>
__device__ void lin16_compute(float (&xl)[16][64], const void* Wv, const void* bv,
                              float* __restrict__ zio, int rbase) {
  const FT* W = (const FT*)Wv;
  const FT* b = (const FT*)bv;
  int lane = threadIdx.x & 63, w = threadIdx.x >> 6;
  int r0 = w * 4;
  float bl = tofl(b[lane]);
  float acc0 = bl, acc1 = bl, acc2 = bl, acc3 = bl;
  for (int k = 0; k < 64; ++k) {
    float wk = tofl(W[k * 64 + lane]);
    acc0 = fmaf(xl[r0 + 0][k], wk, acc0);
    acc1 = fmaf(xl[r0 + 1][k], wk, acc1);
    acc2 = fmaf(xl[r0 + 2][k], wk, acc2);
    acc3 = fmaf(xl[r0 + 3][k], wk, acc3);
  }
  float acc[4] = {sane(acc0), sane(acc1), sane(acc2), sane(acc3)};
#pragma unroll
  for (int j = 0; j < 4; ++j) zio[(rbase + r0 + j) * 64 + lane] = acc[j];
}

__global__ __launch_bounds__(256) void linear16_kernel(float* __restrict__ zio,
                                                       const void* __restrict__ W,
                                                       const void* __restrict__ b,
                                                       const int* __restrict__ fl) {
  __shared__ float xl[16][64];
  int wf = fl[5];
  int tid = threadIdx.x;
  int rbase = blockIdx.x * 16;
  for (int i = tid; i < 1024; i += 256) xl[i >> 6][i & 63] = zio[rbase * 64 + i];
  __syncthreads();
  if (wf)
    lin16_compute<float>(xl, W, b, zio, rbase);
  else
    lin16_compute<bf16>(xl, W, b, zio, rbase);
}

// ---- global mean pool: sorted batch -> one block per graph, no atomics ----
__global__ __launch_bounds__(256) void pool_seg_kernel(const float* __restrict__ z,
                                                       const void* __restrict__ batch,
                                                       const int* __restrict__ fl,
                                                       float* __restrict__ emb) {
  __shared__ float sm[4][64];
  __shared__ int bounds[2];
  int g = blockIdx.x;
  int tid = threadIdx.x, lane = tid & 63, w = tid >> 6;
  int is64 = fl[4];
  if (tid < 2) {
    int target = g + tid;  // lower_bound(batch, target)
    int lo = 0, hi = N_NODES;
    while (lo < hi) {
      int mid = (lo + hi) >> 1;
      if (ldedge(batch, mid, is64) < target) lo = mid + 1; else hi = mid;
    }
    bounds[tid] = lo;
  }
  __syncthreads();
  int beg = bounds[0], end = bounds[1];
  float acc = 0.f;
  for (int r = beg + w; r < end; r += 4) acc += z[r * 64 + lane];
  sm[w][lane] = acc;
  __syncthreads();
  if (w == 0) {
    float v = sm[0][lane] + sm[1][lane] + sm[2][lane] + sm[3][lane];
    float cnt = (float)max(end - beg, 1);
    emb[g * 64 + lane] = sane(v / cnt);
  }
}

// ---- decoder x_hat (64->64->128) ----
template <typename FT>
__device__ void xdec16_compute(float (&zl)[16][64], float (&t1l)[16][64], const void* W1v,
                               const void* b1v, const void* W2v, const void* b2v,
                               float* __restrict__ xout, int rbase) {
  const FT* W1 = (const FT*)W1v;
  const FT* bb1 = (const FT*)b1v;
  const FT* W2 = (const FT*)W2v;
  const FT* bb2 = (const FT*)b2v;
  int lane = threadIdx.x & 63, w = threadIdx.x >> 6;
  int r0 = w * 4;
  float b1l = tofl(bb1[lane]);
  float t0 = b1l, t1 = b1l, t2 = b1l, t3 = b1l;
  for (int k = 0; k < 64; ++k) {
    float wk = tofl(W1[k * 64 + lane]);
    t0 = fmaf(zl[r0 + 0][k], wk, t0);
    t1 = fmaf(zl[r0 + 1][k], wk, t1);
    t2 = fmaf(zl[r0 + 2][k], wk, t2);
    t3 = fmaf(zl[r0 + 3][k], wk, t3);
  }
  t1l[r0 + 0][lane] = fmaxf(t0, 0.f);
  t1l[r0 + 1][lane] = fmaxf(t1, 0.f);
  t1l[r0 + 2][lane] = fmaxf(t2, 0.f);
  t1l[r0 + 3][lane] = fmaxf(t3, 0.f);
  __syncthreads();
  float b2a = tofl(bb2[lane]), b2b = tofl(bb2[64 + lane]);
  float a0[4] = {b2a, b2a, b2a, b2a};
  float a1[4] = {b2b, b2b, b2b, b2b};
  for (int k = 0; k < 64; ++k) {
    float wa = tofl(W2[k * 128 + lane]);
    float wb = tofl(W2[k * 128 + 64 + lane]);
#pragma unroll
    for (int j = 0; j < 4; ++j) {
      float tv = t1l[r0 + j][k];
      a0[j] = fmaf(tv, wa, a0[j]);
      a1[j] = fmaf(tv, wb, a1[j]);
    }
  }
#pragma unroll
  for (int j = 0; j < 4; ++j) {
    int g = rbase + r0 + j;
    xout[g * 128 + lane] = sane(a0[j]);
    xout[g * 128 + 64 + lane] = sane(a1[j]);
  }
}

__global__ __launch_bounds__(256) void xdec16_kernel(
    const float* __restrict__ z, const void* __restrict__ W1, const void* __restrict__ b1,
    const void* __restrict__ W2, const void* __restrict__ b2, const int* __restrict__ fl,
    float* __restrict__ xout) {
  __shared__ float zl[16][64];
  __shared__ float t1l[16][64];
  int wf = fl[5];
  int tid = threadIdx.x;
  int rbase = blockIdx.x * 16;
  for (int i = tid; i < 1024; i += 256) zl[i >> 6][i & 63] = z[rbase * 64 + i];
  __syncthreads();
  if (wf)
    xdec16_compute<float>(zl, t1l, W1, b1, W2, b2, xout, rbase);
  else
    xdec16_compute<bf16>(zl, t1l, W1, b1, W2, b2, xout, rbase);
}

// ---- decoder e_hat (64->64->3) — NO cross-lane reductions.
// Layer 1 like xdec (lane = hidden channel), relu(t) -> padded LDS.
// Layer 2: 12 lanes/wave each own one (row, out-ch) pair, k-loop over
// broadcast LDS reads. Replaces 12 serial wsum (72 dependent DS ops). ----
template <typename FT>
__device__ void edec16_compute(float (&zl)[16][64], float (&t1l)[16][65], float (&W2l)[192],
                               const void* W1v, const void* b1v, const void* b2v,
                               float* __restrict__ eout, int rbase) {
  const FT* W1 = (const FT*)W1v;
  const FT* bb1 = (const FT*)b1v;
  const FT* bb2 = (const FT*)b2v;
  int lane = threadIdx.x & 63, w = threadIdx.x >> 6;
  int r0 = w * 4;
  float b1l = tofl(bb1[lane]);
  float t0 = b1l, t1 = b1l, t2 = b1l, t3 = b1l;
  for (int k = 0; k < 64; ++k) {
    float wk = tofl(W1[k * 64 + lane]);
    t0 = fmaf(zl[r0 + 0][k], wk, t0);
    t1 = fmaf(zl[r0 + 1][k], wk, t1);
    t2 = fmaf(zl[r0 + 2][k], wk, t2);
    t3 = fmaf(zl[r0 + 3][k], wk, t3);
  }
  t1l[r0 + 0][lane] = fmaxf(t0, 0.f);
  t1l[r0 + 1][lane] = fmaxf(t1, 0.f);
  t1l[r0 + 2][lane] = fmaxf(t2, 0.f);
  t1l[r0 + 3][lane] = fmaxf(t3, 0.f);
  __syncthreads();
  // lane -> (j = lane>>4 in [0,4), c = lane&15); active iff c < 3
  int j = lane >> 4, c = lane & 15;
  if (c < 3) {
    int row = r0 + j;
    float acc = tofl(bb2[c]);
#pragma unroll 4
    for (int k = 0; k < 64; ++k) acc = fmaf(t1l[row][k], W2l[k * 3 + c], acc);
    eout[(rbase + row) * 3 + c] = sane(acc);
  }
}

template <typename FT>
__global__ __launch_bounds__(256) void edec16_kernel_t(
    const float* __restrict__ z, const void* __restrict__ W1, const void* __restrict__ b1,
    const void* __restrict__ W2, const void* __restrict__ b2, float* __restrict__ eout) {
  __shared__ float zl[16][64];
  __shared__ float t1l[16][65];  // +1 pad: layer-2 reads hit distinct banks
  __shared__ float W2l[192];
  int tid = threadIdx.x;
  int rbase = blockIdx.x * 16;
  for (int i = tid; i < 1024; i += 256) zl[i >> 6][i & 63] = z[rbase * 64 + i];
  if (tid < 192) W2l[tid] = tofl(((const FT*)W2)[tid]);
  __syncthreads();
  edec16_compute<FT>(zl, t1l, W2l, W1, b1, b2, eout, rbase);
}

__global__ __launch_bounds__(256) void edec16_dispatch(
    const float* __restrict__ z, const void* __restrict__ W1, const void* __restrict__ b1,
    const void* __restrict__ W2, const void* __restrict__ b2, const int* __restrict__ fl,
    float* __restrict__ eout) {
  // unused; selection happens on host is impossible (dtype known only on
  // device), so we branch inside the templated kernel instead. Kept empty.
}

// dtype-branching wrapper (wave-uniform branch, both instantiations inlined)
__global__ __launch_bounds__(256) void edec16_kernel(
    const float* __restrict__ z, const void* __restrict__ W1, const void* __restrict__ b1,
    const void* __restrict__ W2, const void* __restrict__ b2, const int* __restrict__ fl,
    float* __restrict__ eout) {
  __shared__ float zl[16][64];
  __shared__ float t1l[16][65];
  __shared__ float W2l[192];
  int wf = fl[5];
  int tid = threadIdx.x;
  int rbase = blockIdx.x * 16;
  for (int i = tid; i < 1024; i += 256) zl[i >> 6][i & 63] = z[rbase * 64 + i];
  if (tid < 192) W2l[tid] = wf ? ((const float*)W2)[tid] : b2f(((const bf16*)W2)[tid]);
  __syncthreads();
  if (wf)
    edec16_compute<float>(zl, t1l, W2l, W1, b1, b2, eout, rbase);
  else
    edec16_compute<bf16>(zl, t1l, W2l, W1, b1, b2, eout, rbase);
}

extern "C" void kernel_launch(void* const* d_in, const int* in_sizes, int n_in,
                              void* d_out, int out_size, void* d_ws, size_t ws_size,
                              hipStream_t stream) {
  float* outf = (float*)d_out;
  if (out_size != OUT_ELEMS) {
    float sig = 2048.0f + fminf((float)out_size * 1e-4f, 999.f);
    fillsig_kernel<<<(out_size + 255) / 256, 256, 0, stream>>>(outf, out_size, sig);
    return;
  }
  if (n_in < 22 || in_sizes[0] != N_NODES * IN_CH || in_sizes[1] != 2 * N_EDGES) {
    fillsig_kernel<<<(out_size + 255) / 256, 256, 0, stream>>>(outf, out_size, 5000.f);
    return;
  }

  const void* x = d_in[0];
  const void* ei = d_in[1];
  const void* batch = d_in[2];
  const void* W1 = d_in[4];
  const void* as1 = d_in[5];
  const void* ad1 = d_in[6];
  const void* b1 = d_in[7];
  const void* W2 = d_in[8];
  const void* as2 = d_in[9];
  const void* ad2 = d_in[10];
  const void* b2 = d_in[11];
  const void* linW = d_in[12];
  const void* linb = d_in[13];
  const void* xmW1 = d_in[14];
  const void* xmb1 = d_in[15];
  const void* xmW2 = d_in[16];
  const void* xmb2 = d_in[17];
  const void* emW1 = d_in[18];
  const void* emb1 = d_in[19];
  const void* emW2 = d_in[20];
  const void* emb2 = d_in[21];

  float* xhat = outf;                 // [50000,128] f32
  float* ehat = outf + 6400000;       // [50000,3]
  float* zreg = outf + 6550000;       // [50000,64]  o1 -> o2 -> z (f32)
  float* emb = outf + 9750000;        // [500,64]

  bool usews = ws_size >= (size_t)11000000;
  char* base = usews ? (char*)d_ws : (char*)d_out;  // scratch in xhat region if !usews
  int* deg = (int*)(base + 0);
  int* cur = (int*)(base + 200000);
  int* offs = (int*)(base + 400000);
  int* part = (int*)(base + 600016);
  int* flags = (int*)(base + 600272);
  float* ssb = (float*)(base + 600448);
  float* sdb = (float*)(base + 800448);
  int* csr = (int*)(base + 1000448);
  bf16* hbuf = (bf16*)(base + 4200448);  // ends 10,600,448 < 25,600,000

  int err = 0, idx = 0;
  (void)hipGetLastError();
#define CK()                                                                       \
  do {                                                                             \
    ++idx;                                                                         \
    hipError_t e_ = hipGetLastError();                                             \
    if (e_ != hipSuccess && err == 0) err = 8192 + idx * 256 + ((int)e_ & 3) * 64; \
  } while (0)

  zero_kernel<<<(150084 + 255) / 256, 256, 0, stream>>>((int*)base, 150084); CK();
  sniff_x_kernel<<<32, 256, 0, stream>>>((const u16*)x, flags); CK();
  sniff_ei_kernel<<<32, 256, 0, stream>>>((const int*)ei, flags); CK();
  sniff_fin_kernel<<<1, 64, 0, stream>>>(flags); CK();

  hist_kernel<<<N_EDGES / 256, 256, 0, stream>>>(ei, flags, deg); CK();
  scan1_kernel<<<49, 1024, 0, stream>>>(deg, offs, part, N_NODES); CK();
  scan2_kernel<<<1, 64, 0, stream>>>(part, offs, 49, N_NODES); CK();
  scan3_kernel<<<(N_NODES + 255) / 256, 256, 0, stream>>>(offs, part, N_NODES); CK();
  scatter_kernel<<<N_EDGES / 256, 256, 0, stream>>>(ei, flags, offs, cur, csr); CK();

  // layer 1: GAT(128->64) + relu ; o1 (f32) in Z region
  gemm16_kernel<IN_CH><<<N_NODES / 16, 256, 0, stream>>>(x, 0, W1, as1, ad1, flags, hbuf, ssb, sdb); CK();
  gat_aggregate_kernel<<<N_NODES / 4, 256, 0, stream>>>(hbuf, ssb, sdb, offs, csr, b1, flags, zreg, 1); CK();
  // layer 2: GAT(64->64)
  gemm16_kernel<64><<<N_NODES / 16, 256, 0, stream>>>(zreg, 1, W2, as2, ad2, flags, hbuf, ssb, sdb); CK();
  gat_aggregate_kernel<<<N_NODES / 4, 256, 0, stream>>>(hbuf, ssb, sdb, offs, csr, b2, flags, zreg, 0); CK();
  // z = o2 @ lin_W + lin_b, in place
  linear16_kernel<<<N_NODES / 16, 256, 0, stream>>>(zreg, linW, linb, flags); CK();

  // pooled embedding: segmented reduction over sorted batch (no atomics)
  pool_seg_kernel<<<NG, 256, 0, stream>>>(zreg, batch, flags, emb); CK();

  // decoders: e_hat, then x_hat LAST (clobbers d_out-arena scratch if !usews)
  edec16_kernel<<<N_NODES / 16, 256, 0, stream>>>(zreg, emW1, emb1, emW2, emb2, flags, ehat); CK();
  xdec16_kernel<<<N_NODES / 16, 256, 0, stream>>>(zreg, xmW1, xmb1, xmW2, xmb2, flags, xhat); CK();
#undef CK

  if (err != 0) {
    static float s_sent;
    s_sent = (float)err;
    (void)hipMemcpyAsync(d_out, &s_sent, 4, hipMemcpyHostToDevice, stream);
  }
}

// Round 10
// 401.197 us; speedup vs baseline: 1.4832x; 1.0174x over previous
//
#include <hip/hip_runtime.h>
#include <hip/hip_bf16.h>
#include <cstring>

#define N_NODES 50000
#define N_EDGES 800000
#define IN_CH 128
#define NG 500
#define OUT_ELEMS 9782000

using bf16 = __hip_bfloat16;
typedef unsigned short u16;
typedef long long i64;
typedef unsigned long long u64;

__device__ __forceinline__ float b2f(bf16 v) { return __bfloat162float(v); }
__device__ __forceinline__ float tofl(float v) { return v; }
__device__ __forceinline__ float tofl(bf16 v) { return __bfloat162float(v); }
__device__ __forceinline__ float ldflt(const void* p, int i, int f32) {
  return f32 ? ((const float*)p)[i] : b2f(((const bf16*)p)[i]);
}
__device__ __forceinline__ int ldedge(const void* p, int i, int is64) {
  return is64 ? (int)((const i64*)p)[i] : ((const int*)p)[i];
}
__device__ __forceinline__ float sane(float v) {
  if (!isfinite(v)) return 0.f;
  return fminf(fmaxf(v, -65504.f), 65504.f);
}
__device__ __forceinline__ float lrelu(float x) { return x > 0.f ? x : 0.2f * x; }

__device__ __forceinline__ float wsum(float v) {
#pragma unroll
  for (int o = 32; o > 0; o >>= 1) v += __shfl_xor(v, o, 64);
  return v;
}

// d_out is FLOAT32, 9,782,000 elems:
//   xhat@0 (6,400,000) | ehat@6,400,000 (150,000) | zreg@6,550,000 (3,200,000)
//   emb@9,750,000 (32,000)
// Scratch (base = d_ws if ws_size>=17.1MB else d_out; fits in xhat region,
// which xdec overwrites LAST):
//   deg@0 (200,000 B) | bcur@200,000 (200,000; old cur, now bucket counters)
//   offs@400,000 (200,016) | part@600,016 (256) | flags@600,272 (64)
//   ss@600,448 (200,000) | sd@800,448 (200,000) | csr@1,000,448 (3,200,000)
//   hbuf(bf16)@4,200,448 (6,400,000) | tmp(u64)@10,600,448 (6,400,000)
//   -> ends 17,000,448 < 25,600,000

__global__ void zero_kernel(int* __restrict__ p, int n) {
  int i = blockIdx.x * 256 + threadIdx.x;
  if (i < n) p[i] = 0;
}

__global__ void fillsig_kernel(float* __restrict__ out, int n, float v) {
  int i = blockIdx.x * 256 + threadIdx.x;
  if (i < n) out[i] = v;
}

// ---- dtype sniffers (drive the f32-vs-bf16 / int64-vs-int32 decode) ----
__global__ void sniff_x_kernel(const u16* __restrict__ xb, int* __restrict__ fl) {
  int i = blockIdx.x * 256 + threadIdx.x;
  if (i < 8192) {
    u16 u = xb[2 * i];
    int e = (u >> 7) & 0xFF;
    if (e != 0 && (e < 90 || e > 150)) atomicAdd(&fl[7], 1);
  }
}
__global__ void sniff_ei_kernel(const int* __restrict__ ei, int* __restrict__ fl) {
  int i = blockIdx.x * 256 + threadIdx.x;
  if (i < 8192 && ei[2 * i + 1] == 0) atomicAdd(&fl[6], 1);
}
__global__ void sniff_fin_kernel(int* __restrict__ fl) {
  if (blockIdx.x == 0 && threadIdx.x == 0) {
    fl[4] = (fl[6] > 4000) ? 1 : 0;  // ints are int64
    fl[5] = (fl[7] > 2000) ? 1 : 0;  // floats are f32
  }
}

// ---- CSR build ----
__global__ void hist_kernel(const void* __restrict__ ei, const int* __restrict__ fl,
                            int* __restrict__ deg) {
  int is64 = fl[4];
  int e = blockIdx.x * 256 + threadIdx.x;
  if (e < N_EDGES) {
    unsigned d = (unsigned)ldedge(ei, N_EDGES + e, is64);
    if (d < N_NODES) atomicAdd(&deg[d], 1);
  }
}

__global__ __launch_bounds__(1024) void scan1_kernel(const int* __restrict__ deg,
                                                     int* __restrict__ offs,
                                                     int* __restrict__ part, int n) {
  __shared__ int sm[1024];
  int t = threadIdx.x;
  int idx = blockIdx.x * 1024 + t;
  int v = (idx < n) ? deg[idx] : 0;
  sm[t] = v;
  __syncthreads();
  for (int off = 1; off < 1024; off <<= 1) {
    int add = (t >= off) ? sm[t - off] : 0;
    __syncthreads();
    sm[t] += add;
    __syncthreads();
  }
  if (idx < n) offs[idx] = sm[t] - v;
  if (t == 1023) part[blockIdx.x] = sm[1023];
}

__global__ void scan2_kernel(int* __restrict__ part, int* __restrict__ offs, int nb, int n) {
  if (blockIdx.x == 0 && threadIdx.x == 0) {
    int run = 0;
    for (int b = 0; b < nb; ++b) { int t = part[b]; part[b] = run; run += t; }
    offs[n] = run;
  }
}

__global__ void scan3_kernel(int* __restrict__ offs, const int* __restrict__ part, int n) {
  int i = blockIdx.x * 256 + threadIdx.x;
  if (i < n) offs[i] += part[i >> 10];
}

// bucket b covers nodes [b<<10, (b+1)<<10); csr/tmp range = offs slice.
__global__ void bcur_init_kernel(const int* __restrict__ offs, int* __restrict__ bcur) {
  int b = threadIdx.x;
  if (b < 49) bcur[b] = offs[min(b << 10, N_NODES)];
}

// Phase B: bucket-grouped edge records. Per-block LDS histogram, one global
// atomic per (block,bucket) range reservation, contiguous-ish 8B writes.
#define BCHUNK 4096
__global__ __launch_bounds__(256) void bucket_kernel(const void* __restrict__ ei,
                                                     const int* __restrict__ fl,
                                                     int* __restrict__ bcur,
                                                     u64* __restrict__ tmp) {
  __shared__ int hist[64], run[64], gbase[64];
  int tid = threadIdx.x;
  if (tid < 64) { hist[tid] = 0; run[tid] = 0; }
  __syncthreads();
  int is64 = fl[4];
  int base = blockIdx.x * BCHUNK;
#pragma unroll
  for (int k = 0; k < 16; ++k) {
    int e = base + k * 256 + tid;
    if (e < N_EDGES) {
      unsigned d = (unsigned)ldedge(ei, N_EDGES + e, is64);
      if (d < N_NODES) atomicAdd(&hist[d >> 10], 1);
    }
  }
  __syncthreads();
  if (tid < 64) {
    int h = hist[tid];
    gbase[tid] = h ? atomicAdd(&bcur[tid], h) : 0;
  }
  __syncthreads();
#pragma unroll
  for (int k = 0; k < 16; ++k) {
    int e = base + k * 256 + tid;
    if (e < N_EDGES) {
      unsigned d = (unsigned)ldedge(ei, N_EDGES + e, is64);
      if (d < N_NODES) {
        unsigned s = (unsigned)ldedge(ei, e, is64);
        if (s >= N_NODES) s = 0;  // keep count consistent with deg histogram
        int pos = gbase[d >> 10] + atomicAdd(&run[d >> 10], 1);
        tmp[pos] = ((u64)s << 32) | (u64)d;
      }
    }
  }
}

// Phase C: one block per bucket; per-node counters in LDS; csr writes stay
// within one 64KB region per block -> same-XCD L2 merges writebacks.
__global__ __launch_bounds__(1024) void scatter2_kernel(const u64* __restrict__ tmp,
                                                        const int* __restrict__ offs,
                                                        int* __restrict__ csr) {
  __shared__ int lcur[1024];
  int b = blockIdx.x;
  int tid = threadIdx.x;
  lcur[tid] = 0;
  __syncthreads();
  int nodelo = b << 10;
  int beg = offs[min(nodelo, N_NODES)];
  int end = offs[min(nodelo + 1024, N_NODES)];
  for (int i = beg + tid; i < end; i += 1024) {
    u64 v = tmp[i];
    int d = (int)(v & 0xFFFFFFFFu);
    int s = (int)(v >> 32);
    unsigned li = (unsigned)(d - nodelo);
    if (li < 1024) {
      int pos = offs[d] + atomicAdd(&lcur[li], 1);
      if ((unsigned)pos < N_EDGES) csr[pos] = s;
    }
  }
}

// ---- GEMM + attention scores: 16 rows/block, 4 rows/wave, lane = out col ----
template <int FIN, typename FT>
__device__ void gemm16_compute(float (&xl)[16][FIN], const void* Wv, const void* asv,
                               const void* adv, bf16* __restrict__ h, float* __restrict__ ss,
                               float* __restrict__ sd, int rbase) {
  const FT* W = (const FT*)Wv;
  const FT* as_ = (const FT*)asv;
  const FT* ad_ = (const FT*)adv;
  int lane = threadIdx.x & 63, w = threadIdx.x >> 6;
  float a_s = tofl(as_[lane]), a_d = tofl(ad_[lane]);
  int r0 = w * 4;
  float acc0 = 0.f, acc1 = 0.f, acc2 = 0.f, acc3 = 0.f;
  for (int k = 0; k < FIN; ++k) {
    float wk = tofl(W[k * 64 + lane]);
    acc0 = fmaf(xl[r0 + 0][k], wk, acc0);
    acc1 = fmaf(xl[r0 + 1][k], wk, acc1);
    acc2 = fmaf(xl[r0 + 2][k], wk, acc2);
    acc3 = fmaf(xl[r0 + 3][k], wk, acc3);
  }
  float acc[4] = {sane(acc0), sane(acc1), sane(acc2), sane(acc3)};
#pragma unroll
  for (int j = 0; j < 4; ++j) {
    int g = rbase + r0 + j;
    h[g * 64 + lane] = __float2bfloat16(acc[j]);
    float vs = wsum(acc[j] * a_s);
    float vd = wsum(acc[j] * a_d);
    if (lane == 0) { ss[g] = sane(vs); sd[g] = sane(vd); }
  }
}

// xmode 0: external x (dtype per fl[5]); xmode 1: internal f32 buffer.
template <int FIN>
__global__ __launch_bounds__(256) void gemm16_kernel(
    const void* __restrict__ xin, int xmode, const void* __restrict__ W,
    const void* __restrict__ asrc, const void* __restrict__ adst, const int* __restrict__ fl,
    bf16* __restrict__ h, float* __restrict__ ss, float* __restrict__ sd) {
  __shared__ float xl[16][FIN];
  int wf = fl[5];
  int xf = xmode ? 1 : wf;
  int tid = threadIdx.x;
  int rbase = blockIdx.x * 16;
  for (int i = tid; i < 16 * FIN; i += 256) {
    int rr = i / FIN, cc = i % FIN;
    xl[rr][cc] = ldflt(xin, (rbase + rr) * FIN + cc, xf);
  }
  __syncthreads();
  if (wf)
    gemm16_compute<FIN, float>(xl, W, asrc, adst, h, ss, sd, rbase);
  else
    gemm16_compute<FIN, bf16>(xl, W, asrc, adst, h, ss, sd, rbase);
}

// ---- GAT softmax-aggregate: one wave per dst node, lane = channel ----
__global__ __launch_bounds__(256) void gat_aggregate_kernel(
    const bf16* __restrict__ h, const float* __restrict__ ss, const float* __restrict__ sd,
    const int* __restrict__ offs, const int* __restrict__ csr, const void* __restrict__ bias,
    const int* __restrict__ fl, float* __restrict__ outp, int do_relu) {
  int wf = fl[5];
  int lane = threadIdx.x & 63, w = threadIdx.x >> 6;
  int d = blockIdx.x * 4 + w;
  float sdd = sd[d];
  int beg = offs[d], end = offs[d + 1];
  beg = max(0, min(beg, N_EDGES));
  end = max(beg, min(end, N_EDGES));
  float wself = __expf(fminf(lrelu(ss[d] + sdd), 60.f));
  float acc = b2f(h[d * 64 + lane]) * wself;
  float dpart = (lane == 0) ? wself : 0.f;
  for (int cb = beg; cb < end; cb += 64) {
    int j = cb + lane;
    int s = 0;
    float wv = 0.f;
    if (j < end) {
      s = csr[j];
      s = ((unsigned)s < N_NODES) ? s : 0;
      wv = __expf(fminf(lrelu(ss[s] + sdd), 60.f));
    }
    dpart += wv;
    int cnt = min(64, end - cb);
    int t = 0;
    for (; t + 3 < cnt; t += 4) {
      float w0 = __shfl(wv, t, 64), w1 = __shfl(wv, t + 1, 64);
      float w2 = __shfl(wv, t + 2, 64), w3 = __shfl(wv, t + 3, 64);
      int s0 = __shfl(s, t, 64), s1 = __shfl(s, t + 1, 64);
      int s2 = __shfl(s, t + 2, 64), s3 = __shfl(s, t + 3, 64);
      float h0 = b2f(h[s0 * 64 + lane]);
      float h1 = b2f(h[s1 * 64 + lane]);
      float h2 = b2f(h[s2 * 64 + lane]);
      float h3 = b2f(h[s3 * 64 + lane]);
      acc = fmaf(h0, w0, acc);
      acc = fmaf(h1, w1, acc);
      acc = fmaf(h2, w2, acc);
      acc = fmaf(h3, w3, acc);
    }
    for (; t < cnt; ++t) {
      float wt = __shfl(wv, t, 64);
      int st = __shfl(s, t, 64);
      acc = fmaf(b2f(h[st * 64 + lane]), wt, acc);
    }
  }
  float denom = wsum(dpart);
  float res = acc / (denom + 1e-16f) + ldflt(bias, lane, wf);
  if (do_relu) res = fmaxf(res, 0.f);
  outp[d * 64 + lane] = sane(res);
}

// ---- z = o2 @ lin_W + lin_b, in place on f32 Z region ----
template <typename FT>
__device__ void lin16_compute(float (&xl)[16][64], const void* Wv, const void* bv,
                              float* __restrict__ zio, int rbase) {
  const FT* W = (const FT*)Wv;
  const FT* b = (const FT*)bv;
  int lane = threadIdx.x & 63, w = threadIdx.x >> 6;
  int r0 = w * 4;
  float bl = tofl(b[lane]);
  float acc0 = bl, acc1 = bl, acc2 = bl, acc3 = bl;
  for (int k = 0; k < 64; ++k) {
    float wk = tofl(W[k * 64 + lane]);
    acc0 = fmaf(xl[r0 + 0][k], wk, acc0);
    acc1 = fmaf(xl[r0 + 1][k], wk, acc1);
    acc2 = fmaf(xl[r0 + 2][k], wk, acc2);
    acc3 = fmaf(xl[r0 + 3][k], wk, acc3);
  }
  float acc[4] = {sane(acc0), sane(acc1), sane(acc2), sane(acc3)};
#pragma unroll
  for (int j = 0; j < 4; ++j) zio[(rbase + r0 + j) * 64 + lane] = acc[j];
}

__global__ __launch_bounds__(256) void linear16_kernel(float* __restrict__ zio,
                                                       const void* __restrict__ W,
                                                       const void* __restrict__ b,
                                                       const int* __restrict__ fl) {
  __shared__ float xl[16][64];
  int wf = fl[5];
  int tid = threadIdx.x;
  int rbase = blockIdx.x * 16;
  for (int i = tid; i < 1024; i += 256) xl[i >> 6][i & 63] = zio[rbase * 64 + i];
  __syncthreads();
  if (wf)
    lin16_compute<float>(xl, W, b, zio, rbase);
  else
    lin16_compute<bf16>(xl, W, b, zio, rbase);
}

// ---- global mean pool: sorted batch -> one block per graph, no atomics ----
__global__ __launch_bounds__(256) void pool_seg_kernel(const float* __restrict__ z,
                                                       const void* __restrict__ batch,
                                                       const int* __restrict__ fl,
                                                       float* __restrict__ emb) {
  __shared__ float sm[4][64];
  __shared__ int bounds[2];
  int g = blockIdx.x;
  int tid = threadIdx.x, lane = tid & 63, w = tid >> 6;
  int is64 = fl[4];
  if (tid < 2) {
    int target = g + tid;  // lower_bound(batch, target)
    int lo = 0, hi = N_NODES;
    while (lo < hi) {
      int mid = (lo + hi) >> 1;
      if (ldedge(batch, mid, is64) < target) lo = mid + 1; else hi = mid;
    }
    bounds[tid] = lo;
  }
  __syncthreads();
  int beg = bounds[0], end = bounds[1];
  float acc = 0.f;
  for (int r = beg + w; r < end; r += 4) acc += z[r * 64 + lane];
  sm[w][lane] = acc;
  __syncthreads();
  if (w == 0) {
    float v = sm[0][lane] + sm[1][lane] + sm[2][lane] + sm[3][lane];
    float cnt = (float)max(end - beg, 1);
    emb[g * 64 + lane] = sane(v / cnt);
  }
}

// ---- decoder x_hat (64->64->128) ----
template <typename FT>
__device__ void xdec16_compute(float (&zl)[16][64], float (&t1l)[16][64], const void* W1v,
                               const void* b1v, const void* W2v, const void* b2v,
                               float* __restrict__ xout, int rbase) {
  const FT* W1 = (const FT*)W1v;
  const FT* bb1 = (const FT*)b1v;
  const FT* W2 = (const FT*)W2v;
  const FT* bb2 = (const FT*)b2v;
  int lane = threadIdx.x & 63, w = threadIdx.x >> 6;
  int r0 = w * 4;
  float b1l = tofl(bb1[lane]);
  float t0 = b1l, t1 = b1l, t2 = b1l, t3 = b1l;
  for (int k = 0; k < 64; ++k) {
    float wk = tofl(W1[k * 64 + lane]);
    t0 = fmaf(zl[r0 + 0][k], wk, t0);
    t1 = fmaf(zl[r0 + 1][k], wk, t1);
    t2 = fmaf(zl[r0 + 2][k], wk, t2);
    t3 = fmaf(zl[r0 + 3][k], wk, t3);
  }
  t1l[r0 + 0][lane] = fmaxf(t0, 0.f);
  t1l[r0 + 1][lane] = fmaxf(t1, 0.f);
  t1l[r0 + 2][lane] = fmaxf(t2, 0.f);
  t1l[r0 + 3][lane] = fmaxf(t3, 0.f);
  __syncthreads();
  float b2a = tofl(bb2[lane]), b2b = tofl(bb2[64 + lane]);
  float a0[4] = {b2a, b2a, b2a, b2a};
  float a1[4] = {b2b, b2b, b2b, b2b};
  for (int k = 0; k < 64; ++k) {
    float wa = tofl(W2[k * 128 + lane]);
    float wb = tofl(W2[k * 128 + 64 + lane]);
#pragma unroll
    for (int j = 0; j < 4; ++j) {
      float tv = t1l[r0 + j][k];
      a0[j] = fmaf(tv, wa, a0[j]);
      a1[j] = fmaf(tv, wb, a1[j]);
    }
  }
#pragma unroll
  for (int j = 0; j < 4; ++j) {
    int g = rbase + r0 + j;
    xout[g * 128 + lane] = sane(a0[j]);
    xout[g * 128 + 64 + lane] = sane(a1[j]);
  }
}

__global__ __launch_bounds__(256) void xdec16_kernel(
    const float* __restrict__ z, const void* __restrict__ W1, const void* __restrict__ b1,
    const void* __restrict__ W2, const void* __restrict__ b2, const int* __restrict__ fl,
    float* __restrict__ xout) {
  __shared__ float zl[16][64];
  __shared__ float t1l[16][64];
  int wf = fl[5];
  int tid = threadIdx.x;
  int rbase = blockIdx.x * 16;
  for (int i = tid; i < 1024; i += 256) zl[i >> 6][i & 63] = z[rbase * 64 + i];
  __syncthreads();
  if (wf)
    xdec16_compute<float>(zl, t1l, W1, b1, W2, b2, xout, rbase);
  else
    xdec16_compute<bf16>(zl, t1l, W1, b1, W2, b2, xout, rbase);
}

// ---- decoder e_hat (64->64->3): no cross-lane reductions ----
template <typename FT>
__device__ void edec16_compute(float (&zl)[16][64], float (&t1l)[16][65], float (&W2l)[192],
                               const void* W1v, const void* b1v, const void* b2v,
                               float* __restrict__ eout, int rbase) {
  const FT* W1 = (const FT*)W1v;
  const FT* bb1 = (const FT*)b1v;
  const FT* bb2 = (const FT*)b2v;
  int lane = threadIdx.x & 63, w = threadIdx.x >> 6;
  int r0 = w * 4;
  float b1l = tofl(bb1[lane]);
  float t0 = b1l, t1 = b1l, t2 = b1l, t3 = b1l;
  for (int k = 0; k < 64; ++k) {
    float wk = tofl(W1[k * 64 + lane]);
    t0 = fmaf(zl[r0 + 0][k], wk, t0);
    t1 = fmaf(zl[r0 + 1][k], wk, t1);
    t2 = fmaf(zl[r0 + 2][k], wk, t2);
    t3 = fmaf(zl[r0 + 3][k], wk, t3);
  }
  t1l[r0 + 0][lane] = fmaxf(t0, 0.f);
  t1l[r0 + 1][lane] = fmaxf(t1, 0.f);
  t1l[r0 + 2][lane] = fmaxf(t2, 0.f);
  t1l[r0 + 3][lane] = fmaxf(t3, 0.f);
  __syncthreads();
  int j = lane >> 4, c = lane & 15;
  if (c < 3) {
    int row = r0 + j;
    float acc = tofl(bb2[c]);
#pragma unroll 4
    for (int k = 0; k < 64; ++k) acc = fmaf(t1l[row][k], W2l[k * 3 + c], acc);
    eout[(rbase + row) * 3 + c] = sane(acc);
  }
}

__global__ __launch_bounds__(256) void edec16_kernel(
    const float* __restrict__ z, const void* __restrict__ W1, const void* __restrict__ b1,
    const void* __restrict__ W2, const void* __restrict__ b2, const int* __restrict__ fl,
    float* __restrict__ eout) {
  __shared__ float zl[16][64];
  __shared__ float t1l[16][65];
  __shared__ float W2l[192];
  int wf = fl[5];
  int tid = threadIdx.x;
  int rbase = blockIdx.x * 16;
  for (int i = tid; i < 1024; i += 256) zl[i >> 6][i & 63] = z[rbase * 64 + i];
  if (tid < 192) W2l[tid] = wf ? ((const float*)W2)[tid] : b2f(((const bf16*)W2)[tid]);
  __syncthreads();
  if (wf)
    edec16_compute<float>(zl, t1l, W2l, W1, b1, b2, eout, rbase);
  else
    edec16_compute<bf16>(zl, t1l, W2l, W1, b1, b2, eout, rbase);
}

extern "C" void kernel_launch(void* const* d_in, const int* in_sizes, int n_in,
                              void* d_out, int out_size, void* d_ws, size_t ws_size,
                              hipStream_t stream) {
  float* outf = (float*)d_out;
  if (out_size != OUT_ELEMS) {
    float sig = 2048.0f + fminf((float)out_size * 1e-4f, 999.f);
    fillsig_kernel<<<(out_size + 255) / 256, 256, 0, stream>>>(outf, out_size, sig);
    return;
  }
  if (n_in < 22 || in_sizes[0] != N_NODES * IN_CH || in_sizes[1] != 2 * N_EDGES) {
    fillsig_kernel<<<(out_size + 255) / 256, 256, 0, stream>>>(outf, out_size, 5000.f);
    return;
  }

  const void* x = d_in[0];
  const void* ei = d_in[1];
  const void* batch = d_in[2];
  const void* W1 = d_in[4];
  const void* as1 = d_in[5];
  const void* ad1 = d_in[6];
  const void* b1 = d_in[7];
  const void* W2 = d_in[8];
  const void* as2 = d_in[9];
  const void* ad2 = d_in[10];
  const void* b2 = d_in[11];
  const void* linW = d_in[12];
  const void* linb = d_in[13];
  const void* xmW1 = d_in[14];
  const void* xmb1 = d_in[15];
  const void* xmW2 = d_in[16];
  const void* xmb2 = d_in[17];
  const void* emW1 = d_in[18];
  const void* emb1 = d_in[19];
  const void* emW2 = d_in[20];
  const void* emb2 = d_in[21];

  float* xhat = outf;                 // [50000,128] f32
  float* ehat = outf + 6400000;       // [50000,3]
  float* zreg = outf + 6550000;       // [50000,64]  o1 -> o2 -> z (f32)
  float* emb = outf + 9750000;        // [500,64]

  bool usews = ws_size >= (size_t)17100000;
  char* base = usews ? (char*)d_ws : (char*)d_out;  // scratch in xhat region if !usews
  int* deg = (int*)(base + 0);
  int* bcur = (int*)(base + 200000);
  int* offs = (int*)(base + 400000);
  int* part = (int*)(base + 600016);
  int* flags = (int*)(base + 600272);
  float* ssb = (float*)(base + 600448);
  float* sdb = (float*)(base + 800448);
  int* csr = (int*)(base + 1000448);
  bf16* hbuf = (bf16*)(base + 4200448);
  u64* tmp = (u64*)(base + 10600448);  // ends 17,000,448 < 25,600,000

  int err = 0, idx = 0;
  (void)hipGetLastError();
#define CK()                                                                       \
  do {                                                                             \
    ++idx;                                                                         \
    hipError_t e_ = hipGetLastError();                                             \
    if (e_ != hipSuccess && err == 0) err = 8192 + idx * 256 + ((int)e_ & 3) * 64; \
  } while (0)

  zero_kernel<<<(150084 + 255) / 256, 256, 0, stream>>>((int*)base, 150084); CK();
  sniff_x_kernel<<<32, 256, 0, stream>>>((const u16*)x, flags); CK();
  sniff_ei_kernel<<<32, 256, 0, stream>>>((const int*)ei, flags); CK();
  sniff_fin_kernel<<<1, 64, 0, stream>>>(flags); CK();

  hist_kernel<<<N_EDGES / 256, 256, 0, stream>>>(ei, flags, deg); CK();
  scan1_kernel<<<49, 1024, 0, stream>>>(deg, offs, part, N_NODES); CK();
  scan2_kernel<<<1, 64, 0, stream>>>(part, offs, 49, N_NODES); CK();
  scan3_kernel<<<(N_NODES + 255) / 256, 256, 0, stream>>>(offs, part, N_NODES); CK();
  // two-phase bucket scatter (write-locality fix for csr build)
  bcur_init_kernel<<<1, 64, 0, stream>>>(offs, bcur); CK();
  bucket_kernel<<<(N_EDGES + BCHUNK - 1) / BCHUNK, 256, 0, stream>>>(ei, flags, bcur, tmp); CK();
  scatter2_kernel<<<49, 1024, 0, stream>>>(tmp, offs, csr); CK();

  // layer 1: GAT(128->64) + relu ; o1 (f32) in Z region
  gemm16_kernel<IN_CH><<<N_NODES / 16, 256, 0, stream>>>(x, 0, W1, as1, ad1, flags, hbuf, ssb, sdb); CK();
  gat_aggregate_kernel<<<N_NODES / 4, 256, 0, stream>>>(hbuf, ssb, sdb, offs, csr, b1, flags, zreg, 1); CK();
  // layer 2: GAT(64->64)
  gemm16_kernel<64><<<N_NODES / 16, 256, 0, stream>>>(zreg, 1, W2, as2, ad2, flags, hbuf, ssb, sdb); CK();
  gat_aggregate_kernel<<<N_NODES / 4, 256, 0, stream>>>(hbuf, ssb, sdb, offs, csr, b2, flags, zreg, 0); CK();
  // z = o2 @ lin_W + lin_b, in place
  linear16_kernel<<<N_NODES / 16, 256, 0, stream>>>(zreg, linW, linb, flags); CK();

  // pooled embedding: segmented reduction over sorted batch (no atomics)
  pool_seg_kernel<<<NG, 256, 0, stream>>>(zreg, batch, flags, emb); CK();

  // decoders: e_hat, then x_hat LAST (clobbers d_out-arena scratch if !usews)
  edec16_kernel<<<N_NODES / 16, 256, 0, stream>>>(zreg, emW1, emb1, emW2, emb2, flags, ehat); CK();
  xdec16_kernel<<<N_NODES / 16, 256, 0, stream>>>(zreg, xmW1, xmb1, xmW2, xmb2, flags, xhat); CK();
#undef CK

  if (err != 0) {
    static float s_sent;
    s_sent = (float)err;
    (void)hipMemcpyAsync(d_out, &s_sent, 4, hipMemcpyHostToDevice, stream);
  }
}